// Round 2
// baseline (2704.888 us; speedup 1.0000x reference)
//
#include <hip/hip_runtime.h>
#include <hip/hip_bf16.h>

// All reference tensors are float32 -> device buffers are f32 (in AND out).

__device__ __forceinline__ float toF(float v) { return v; }
__device__ __forceinline__ void storeF(float* p, float v) { *p = v; }

// ---------------------------------------------------------------------------
// Fused conv3x3(VALID) + bias + maxpool2x2 + ReLU.
// Thread -> one pooled output position (and OCB output channels); computes the
// 2x2 conv window from a 4x4 input patch. Weights staged in LDS, ci-chunked.
// Block = SPT spatial threads x OCS oc-groups.
// ---------------------------------------------------------------------------
template<int CIN, int HIN, int PH, int OCB, int SPT, int OCS, int CICH, int COUT>
__global__ __launch_bounds__(SPT*OCS) void k_conv_pool_relu(
    const float* __restrict__ in, const float* __restrict__ w,
    const float* __restrict__ bias, float* __restrict__ out)
{
    constexpr int BT    = SPT * OCS;
    constexpr int WIN   = HIN;
    constexpr int PW    = PH;
    constexpr int OCBLK = OCB * OCS;
    constexpr int WSTR  = CICH * 9 + 1;   // pad: de-conflict oc-group LDS banks

    __shared__ float wsh[OCBLK * WSTR];

    const int b   = blockIdx.z;
    const int oc0 = blockIdx.y * OCBLK;
    const int t   = threadIdx.x;
    const int spl = (OCS == 1) ? t : (t % SPT);
    const int ocq = (OCS == 1) ? 0 : (t / SPT);
    const int sp  = blockIdx.x * SPT + spl;
    const bool active = sp < PH * PW;
    const int py = active ? (sp / PW) : 0;
    const int px = active ? (sp % PW) : 0;

    float acc[OCB][4];
#pragma unroll
    for (int j = 0; j < OCB; ++j) {
        acc[j][0] = acc[j][1] = acc[j][2] = acc[j][3] = 0.f;
    }

    const float* inb = in + (size_t)b * CIN * HIN * WIN;

    for (int c0 = 0; c0 < CIN; c0 += CICH) {
        __syncthreads();
        for (int i = t; i < OCBLK * CICH * 9; i += BT) {
            int j = i / (CICH * 9);
            int r = i - j * (CICH * 9);
            wsh[j * WSTR + r] = w[((size_t)(oc0 + j) * CIN + c0) * 9 + r];
        }
        __syncthreads();

        for (int ci = 0; ci < CICH; ++ci) {
            const float* inc = inb + (size_t)(c0 + ci) * HIN * WIN
                             + (2 * py) * WIN + 2 * px;
            float patch[4][4];
#pragma unroll
            for (int r = 0; r < 4; ++r)
#pragma unroll
                for (int c = 0; c < 4; ++c)
                    patch[r][c] = inc[r * WIN + c];

#pragma unroll
            for (int j = 0; j < OCB; ++j) {
                const float* wp = &wsh[(ocq * OCB + j) * WSTR + ci * 9];
#pragma unroll
                for (int kh = 0; kh < 3; ++kh)
#pragma unroll
                    for (int kw = 0; kw < 3; ++kw) {
                        float wv = wp[kh * 3 + kw];
                        acc[j][0] = fmaf(patch[kh][kw],         wv, acc[j][0]);
                        acc[j][1] = fmaf(patch[kh][kw + 1],     wv, acc[j][1]);
                        acc[j][2] = fmaf(patch[kh + 1][kw],     wv, acc[j][2]);
                        acc[j][3] = fmaf(patch[kh + 1][kw + 1], wv, acc[j][3]);
                    }
            }
        }
    }

    if (active) {
#pragma unroll
        for (int j = 0; j < OCB; ++j) {
            int oc = oc0 + ocq * OCB + j;
            float m = fmaxf(fmaxf(acc[j][0], acc[j][1]),
                            fmaxf(acc[j][2], acc[j][3]));
            m += bias[oc];
            m = fmaxf(m, 0.f);
            out[(((size_t)b * COUT + oc) * PH + py) * PW + px] = m;
        }
    }
}

// ---------------------------------------------------------------------------
// K-split tiled GEMM: C_partial[kz] = A(128xK, rowmajor) x B(KxN rowmajor)
// Block tile 64x64, thread micro-tile 4x4, LDS-staged, f32 accumulate.
// ---------------------------------------------------------------------------
__global__ __launch_bounds__(256) void k_gemm_part(
    const float* __restrict__ A, const float* __restrict__ B,
    float* __restrict__ P, int N, int K, int KS)
{
    __shared__ __align__(16) float As[32][68];   // [k][m], padded
    __shared__ __align__(16) float Bs[32][68];   // [k][n], padded

    const int t  = threadIdx.x;
    const int bm = blockIdx.x, bn = blockIdx.y, kz = blockIdx.z;
    const int kchunk = K / KS;
    const int k0 = kz * kchunk, k1 = k0 + kchunk;
    const int tm = t & 15, tn = t >> 4;

    float acc[4][4];
#pragma unroll
    for (int i = 0; i < 4; ++i)
#pragma unroll
        for (int j = 0; j < 4; ++j) acc[i][j] = 0.f;

    for (int kc = k0; kc < k1; kc += 32) {
        __syncthreads();
#pragma unroll
        for (int i = t; i < 64 * 32; i += 256) {
            int m_l = i >> 5, k_l = i & 31;
            As[k_l][m_l] = A[(size_t)(bm * 64 + m_l) * K + kc + k_l];
        }
#pragma unroll
        for (int i = t; i < 32 * 64; i += 256) {
            int k_l = i >> 6, n_l = i & 63;
            Bs[k_l][n_l] = B[(size_t)(kc + k_l) * N + bn * 64 + n_l];
        }
        __syncthreads();
#pragma unroll
        for (int k = 0; k < 32; ++k) {
            float4 av = *(const float4*)&As[k][tm * 4];
            float4 bv = *(const float4*)&Bs[k][tn * 4];
            float a_[4] = {av.x, av.y, av.z, av.w};
            float b_[4] = {bv.x, bv.y, bv.z, bv.w};
#pragma unroll
            for (int i = 0; i < 4; ++i)
#pragma unroll
                for (int j = 0; j < 4; ++j)
                    acc[i][j] = fmaf(a_[i], b_[j], acc[i][j]);
        }
    }

    float* Pk = P + (size_t)kz * 128 * N;
#pragma unroll
    for (int i = 0; i < 4; ++i) {
        int m = bm * 64 + tm * 4 + i;
#pragma unroll
        for (int j = 0; j < 4; ++j) {
            int n = bn * 64 + tn * 4 + j;
            Pk[(size_t)m * N + n] = acc[i][j];
        }
    }
}

// sum K-split partials + bias (+ tanh)
template<bool TANH>
__global__ void k_fc_epi(const float* __restrict__ P, const float* __restrict__ bias,
                         float* __restrict__ out, int MN, int N, int KS)
{
    int i = blockIdx.x * 256 + threadIdx.x;
    if (i >= MN) return;
    float s = 0.f;
    for (int z = 0; z < KS; ++z) s += P[(size_t)z * MN + i];
    s += bias[i % N];
    if (TANH) s = tanhf(s);
    out[i] = s;
}

// FC3: (128x2048) x (2048x62), K-split partials. grid=(128,KS), block=64.
__global__ __launch_bounds__(64) void k_fc3_part(
    const float* __restrict__ A, const float* __restrict__ B,
    float* __restrict__ P, int K, int N, int KS)
{
    const int m = blockIdx.x, kz = blockIdx.y;
    const int n = threadIdx.x;
    const int kchunk = K / KS;
    if (n < N) {
        float acc = 0.f;
        const float* Am = A + (size_t)m * K;
        const int ke = (kz + 1) * kchunk;
        for (int k = kz * kchunk; k < ke; ++k)
            acc = fmaf(Am[k], B[(size_t)k * N + n], acc);
        P[((size_t)kz * 128 + m) * N + n] = acc;
    }
}

// Per-batch DMP segment prep: idx/round/clip, amplitudes, exclusive cumsum of
// segment end-offsets -> start positions. 1 block x 128 threads (thread = b).
__global__ void k_traj_start(const float* __restrict__ p, const float* __restrict__ td,
                             float* __restrict__ starts, float* __restrict__ sa,
                             int* __restrict__ sidx)
{
    int b = threadIdx.x;
    const float* pb = p + b * 62;
    float cx = pb[0], cy = pb[1];
    for (int s = 0; s < 20; ++s) {
        float f  = pb[2 + 3 * s];
        float a0 = pb[3 + 3 * s];
        float a1 = pb[4 + 3 * s];
        int idx = (int)fminf(fmaxf(rintf(f), 0.f), 999.f);
        int bs = b * 20 + s;
        sidx[bs] = idx;
        sa[bs * 2 + 0] = a0;
        sa[bs * 2 + 1] = a1;
        starts[bs * 2 + 0] = cx;
        starts[bs * 2 + 1] = cy;
        cx += td[((size_t)idx * 200 + 199) * 2 + 0] * a0;
        cy += td[((size_t)idx * 200 + 199) * 2 + 1] * a1;
    }
}

// traj = dict[idx] * a + start, broadcast over the 200 points. block per (b,s).
__global__ void k_traj_main(const float* __restrict__ td, const float* __restrict__ starts,
                            const float* __restrict__ sa, const int* __restrict__ sidx,
                            float* __restrict__ out)
{
    int bs = blockIdx.x;
    int idx = sidx[bs];
    float a0 = sa[bs * 2 + 0], a1 = sa[bs * 2 + 1];
    float s0 = starts[bs * 2 + 0], s1 = starts[bs * 2 + 1];
    const float* row = td + (size_t)idx * 400;
    float* o = out + (size_t)bs * 400;
    for (int e = threadIdx.x; e < 400; e += blockDim.x) {
        float v = row[e];
        float r = (e & 1) ? fmaf(v, a1, s1) : fmaf(v, a0, s0);
        o[e] = r;
    }
}

// ---------------------------------------------------------------------------
extern "C" void kernel_launch(void* const* d_in, const int* in_sizes, int n_in,
                              void* d_out, int out_size, void* d_ws, size_t ws_size,
                              hipStream_t stream)
{
    (void)in_sizes; (void)n_in; (void)out_size; (void)ws_size;

    const float* x   = (const float*)d_in[0];
    const float* w1  = (const float*)d_in[1];
    const float* b1  = (const float*)d_in[2];
    const float* w2  = (const float*)d_in[3];
    const float* b2  = (const float*)d_in[4];
    const float* w3  = (const float*)d_in[5];
    const float* b3  = (const float*)d_in[6];
    const float* w4  = (const float*)d_in[7];
    const float* b4  = (const float*)d_in[8];
    const float* fw1 = (const float*)d_in[9];
    const float* fb1 = (const float*)d_in[10];
    const float* fw2 = (const float*)d_in[11];
    const float* fb2 = (const float*)d_in[12];
    const float* fw3 = (const float*)d_in[13];
    const float* fb3 = (const float*)d_in[14];
    const float* td  = (const float*)d_in[15];
    float* out = (float*)d_out;
    char* ws = (char*)d_ws;

    constexpr size_t H1 = 128ull * 64 * 49 * 49;    // 19,668,992 f32
    constexpr size_t H3 = 128ull * 256 * 10 * 10;   //  3,276,800 f32
    constexpr size_t H4 = 128ull * 512 * 16;        //  1,048,576 f32

    // Layout (peak = (H1+H2)*4 = 113.3 MB):
    //   conv1/conv2 live:  h1 [0, H1*4)   h2 [H1*4, H1*4+H2*4)
    //   after conv2 h1 is dead; h3/h4/FC buffers reuse its region.
    float* h1 = (float*)ws;
    float* h2 = (float*)(ws + H1 * 4);
    float* h3 = (float*)ws;
    float* h4 = (float*)(ws + H3 * 4);
    char* q = ws + (H3 + H4) * 4;
    float* part = (float*)q;          q += 4ull * 128 * 2048 * 4;
    float* a1 = (float*)q;            q += 128ull * 2048 * 4;
    float* a2 = (float*)q;            q += 128ull * 2048 * 4;
    float* p = (float*)q;             q += 128ull * 62 * 4;
    float* starts = (float*)q;        q += 128ull * 20 * 2 * 4;
    float* sa = (float*)q;            q += 128ull * 20 * 2 * 4;
    int* sidx = (int*)q;

    // conv1: 3->64, 100 -> pool 49
    k_conv_pool_relu<3, 100, 49, 8, 256, 1, 3, 64>
        <<<dim3(10, 8, 128), 256, 0, stream>>>(x, w1, b1, h1);
    // conv2: 64->128, 49 -> pool 23
    k_conv_pool_relu<64, 49, 23, 8, 192, 1, 16, 128>
        <<<dim3(3, 16, 128), 192, 0, stream>>>(h1, w2, b2, h2);
    // conv3: 128->256, 23 -> pool 10
    k_conv_pool_relu<128, 23, 10, 8, 128, 2, 16, 256>
        <<<dim3(1, 16, 128), 256, 0, stream>>>(h2, w3, b3, h3);
    // conv4: 256->512, 10 -> pool 4
    k_conv_pool_relu<256, 10, 4, 2, 16, 16, 16, 512>
        <<<dim3(1, 16, 128), 256, 0, stream>>>(h3, w4, b4, h4);

    // FC1: (128x8192)x(8192x2048), tanh
    k_gemm_part<<<dim3(2, 32, 4), 256, 0, stream>>>(h4, fw1, part, 2048, 8192, 4);
    k_fc_epi<true><<<(128 * 2048 + 255) / 256, 256, 0, stream>>>(
        part, fb1, a1, 128 * 2048, 2048, 4);
    // FC2: (128x2048)x(2048x2048), tanh
    k_gemm_part<<<dim3(2, 32, 4), 256, 0, stream>>>(a1, fw2, part, 2048, 2048, 4);
    k_fc_epi<true><<<(128 * 2048 + 255) / 256, 256, 0, stream>>>(
        part, fb2, a2, 128 * 2048, 2048, 4);
    // FC3: (128x2048)x(2048x62), no act
    k_fc3_part<<<dim3(128, 4), 64, 0, stream>>>(a2, fw3, part, 2048, 62, 4);
    k_fc_epi<false><<<(128 * 62 + 255) / 256, 256, 0, stream>>>(
        part, fb3, p, 128 * 62, 62, 4);

    // trajectory composition
    k_traj_start<<<1, 128, 0, stream>>>(p, td, starts, sa, sidx);
    k_traj_main<<<2560, 256, 0, stream>>>(td, starts, sa, sidx, out);
}

// Round 3
// 1430.038 us; speedup vs baseline: 1.8915x; 1.8915x over previous
//
#include <hip/hip_runtime.h>
#include <hip/hip_bf16.h>

typedef __attribute__((ext_vector_type(8))) short s8v;
typedef __attribute__((ext_vector_type(4))) float f4v;

union V8 { s8v v; short s[8]; };

__device__ __forceinline__ short f2bf(float v){
    union { __hip_bfloat16 b; short u; } x;
    x.b = __float2bfloat16(v);
    return x.u;
}
__device__ __forceinline__ float bf2f(short u){
    union { short u; __hip_bfloat16 b; } x;
    x.u = u;
    return __bfloat162float(x.b);
}
__device__ __forceinline__ void splitf(float v, short& h, short& l){
    h = f2bf(v);
    l = f2bf(v - bf2f(h));
}

// ---------------------------------------------------------------------------
// Direct conv (kept for conv1 only: CIN=3, K=27 too small for GEMM tiling).
// ---------------------------------------------------------------------------
template<int CIN, int HIN, int PH, int OCB, int SPT, int OCS, int CICH, int COUT>
__global__ __launch_bounds__(SPT*OCS) void k_conv_pool_relu(
    const float* __restrict__ in, const float* __restrict__ w,
    const float* __restrict__ bias, float* __restrict__ out)
{
    constexpr int BT    = SPT * OCS;
    constexpr int WIN   = HIN;
    constexpr int PW    = PH;
    constexpr int OCBLK = OCB * OCS;
    constexpr int WSTR  = CICH * 9 + 1;

    __shared__ float wsh[OCBLK * WSTR];

    const int b   = blockIdx.z;
    const int oc0 = blockIdx.y * OCBLK;
    const int t   = threadIdx.x;
    const int spl = (OCS == 1) ? t : (t % SPT);
    const int ocq = (OCS == 1) ? 0 : (t / SPT);
    const int sp  = blockIdx.x * SPT + spl;
    const bool active = sp < PH * PW;
    const int py = active ? (sp / PW) : 0;
    const int px = active ? (sp % PW) : 0;

    float acc[OCB][4];
#pragma unroll
    for (int j = 0; j < OCB; ++j)
        acc[j][0] = acc[j][1] = acc[j][2] = acc[j][3] = 0.f;

    const float* inb = in + (size_t)b * CIN * HIN * WIN;

    for (int c0 = 0; c0 < CIN; c0 += CICH) {
        __syncthreads();
        for (int i = t; i < OCBLK * CICH * 9; i += BT) {
            int j = i / (CICH * 9);
            int r = i - j * (CICH * 9);
            wsh[j * WSTR + r] = w[((size_t)(oc0 + j) * CIN + c0) * 9 + r];
        }
        __syncthreads();

        for (int ci = 0; ci < CICH; ++ci) {
            const float* inc = inb + (size_t)(c0 + ci) * HIN * WIN
                             + (2 * py) * WIN + 2 * px;
            float patch[4][4];
#pragma unroll
            for (int r = 0; r < 4; ++r)
#pragma unroll
                for (int c = 0; c < 4; ++c)
                    patch[r][c] = inc[r * WIN + c];

#pragma unroll
            for (int j = 0; j < OCB; ++j) {
                const float* wp = &wsh[(ocq * OCB + j) * WSTR + ci * 9];
#pragma unroll
                for (int kh = 0; kh < 3; ++kh)
#pragma unroll
                    for (int kw = 0; kw < 3; ++kw) {
                        float wv = wp[kh * 3 + kw];
                        acc[j][0] = fmaf(patch[kh][kw],         wv, acc[j][0]);
                        acc[j][1] = fmaf(patch[kh][kw + 1],     wv, acc[j][1]);
                        acc[j][2] = fmaf(patch[kh + 1][kw],     wv, acc[j][2]);
                        acc[j][3] = fmaf(patch[kh + 1][kw + 1], wv, acc[j][3]);
                    }
            }
        }
    }

    if (active) {
#pragma unroll
        for (int j = 0; j < OCB; ++j) {
            int oc = oc0 + ocq * OCB + j;
            float m = fmaxf(fmaxf(acc[j][0], acc[j][1]),
                            fmaxf(acc[j][2], acc[j][3]));
            m = fmaxf(m + bias[oc], 0.f);
            out[(((size_t)b * COUT + oc) * PH + py) * PW + px] = m;
        }
    }
}

// ---------------------------------------------------------------------------
// Unified split-bf16 MFMA GEMM.
// MODE 0: implicit-GEMM conv. M-rows = pooled_idx*4+quad (per image); A gathered
//         im2col via offs[k] (precomputed in LDS); B = conv weight [oc][ci*9]
//         (already B^T-contiguous); epilogue = in-register 2x2 maxpool (the 4
//         quad values are exactly one lane's 4 C-regs) + bias + ReLU, stores
//         pooled NCHW f32.
// MODE 1: dense FC, A [M=128][K] rowmajor, B [K][N], epilogue bias+tanh.
// Split numerics: v = hi + lo (bf16 each); C += Ah*Bh + Ah*Bl + Al*Bh.
// Block: 256 thr = 4 waves; tile 64x64; wave = 2x2 subtiles of 16x16; BK=32.
// ---------------------------------------------------------------------------
template<int MODE, int K, int N, int CIN, int HIN, int PPH, int PPW, int COUT, int TPI>
__global__ __launch_bounds__(256) void k_gemm_mfma(
    const float* __restrict__ A, const float* __restrict__ B,
    const float* __restrict__ bias, float* __restrict__ out)
{
    __shared__ short Ah[64][40], Al[64][40], Bh[64][40], Bl[64][40];
    __shared__ int offs[MODE == 0 ? K : 1];

    const int t    = threadIdx.x;
    const int lane = t & 63;
    const int wave = t >> 6;
    const int n0   = blockIdx.y * 64;
    const int srow = t & 63;   // staging row (A-row / B-n)
    const int skq  = t >> 6;   // staging k-octet

    long rb = 0;
    int b = 0, ptile = 0;
    if (MODE == 0) {
        b = blockIdx.x / TPI;
        ptile = blockIdx.x - b * TPI;
        int pl = ptile * 16 + (srow >> 2);
        int quad = srow & 3;
        int py = 0, px = 0;
        if (pl < PPH * PPW) { py = pl / PPW; px = pl - py * PPW; }
        rb = (long)b * CIN * HIN * HIN
           + (long)(2 * py + (quad >> 1)) * HIN + (2 * px + (quad & 1));
        for (int k = t; k < K; k += 256) {
            int ci = k / 9, r = k - ci * 9;
            int kh = r / 3, kw = r - kh * 3;
            offs[k] = ci * HIN * HIN + kh * HIN + kw;
        }
    } else {
        rb = (long)(blockIdx.x * 64 + srow) * K;
    }
    const float* Ar = A + rb;

    const int wm = (wave & 1) * 32;
    const int wn = (wave >> 1) * 32;

    f4v acc[2][2];
    const f4v z4 = {0.f, 0.f, 0.f, 0.f};
    acc[0][0] = z4; acc[0][1] = z4; acc[1][0] = z4; acc[1][1] = z4;

    for (int kk = 0; kk < K; kk += 32) {
        __syncthreads();   // also covers the offs prologue on first iteration
        V8 ha, la, hb, lb;
        const int kb = kk + skq * 8;
        if (MODE == 0) {
#pragma unroll
            for (int j = 0; j < 8; ++j) {
                float v = Ar[offs[kb + j]];
                splitf(v, ha.s[j], la.s[j]);
            }
            const float* bp = B + (size_t)(n0 + srow) * K + kb;
            float4 v0 = *(const float4*)bp;
            float4 v1 = *(const float4*)(bp + 4);
            splitf(v0.x, hb.s[0], lb.s[0]); splitf(v0.y, hb.s[1], lb.s[1]);
            splitf(v0.z, hb.s[2], lb.s[2]); splitf(v0.w, hb.s[3], lb.s[3]);
            splitf(v1.x, hb.s[4], lb.s[4]); splitf(v1.y, hb.s[5], lb.s[5]);
            splitf(v1.z, hb.s[6], lb.s[6]); splitf(v1.w, hb.s[7], lb.s[7]);
        } else {
            const float* ap = Ar + kb;
            float4 a0 = *(const float4*)ap;
            float4 a1 = *(const float4*)(ap + 4);
            splitf(a0.x, ha.s[0], la.s[0]); splitf(a0.y, ha.s[1], la.s[1]);
            splitf(a0.z, ha.s[2], la.s[2]); splitf(a0.w, ha.s[3], la.s[3]);
            splitf(a1.x, ha.s[4], la.s[4]); splitf(a1.y, ha.s[5], la.s[5]);
            splitf(a1.z, ha.s[6], la.s[6]); splitf(a1.w, ha.s[7], la.s[7]);
            const float* bp = B + (size_t)kb * N + n0 + srow;
#pragma unroll
            for (int j = 0; j < 8; ++j)
                splitf(bp[(size_t)j * N], hb.s[j], lb.s[j]);
        }
        *(s8v*)&Ah[srow][skq * 8] = ha.v;
        *(s8v*)&Al[srow][skq * 8] = la.v;
        *(s8v*)&Bh[srow][skq * 8] = hb.v;
        *(s8v*)&Bl[srow][skq * 8] = lb.v;
        __syncthreads();

        const int fm = lane & 15;
        const int fk = (lane >> 4) * 8;
        s8v A0h = *(const s8v*)&Ah[wm + fm][fk];
        s8v A0l = *(const s8v*)&Al[wm + fm][fk];
        s8v A1h = *(const s8v*)&Ah[wm + 16 + fm][fk];
        s8v A1l = *(const s8v*)&Al[wm + 16 + fm][fk];
        s8v B0h = *(const s8v*)&Bh[wn + fm][fk];
        s8v B0l = *(const s8v*)&Bl[wn + fm][fk];
        s8v B1h = *(const s8v*)&Bh[wn + 16 + fm][fk];
        s8v B1l = *(const s8v*)&Bl[wn + 16 + fm][fk];
#define MF(a_, b_, c_) c_ = __builtin_amdgcn_mfma_f32_16x16x32_bf16(a_, b_, c_, 0, 0, 0)
        MF(A0h, B0h, acc[0][0]); MF(A0h, B0l, acc[0][0]); MF(A0l, B0h, acc[0][0]);
        MF(A0h, B1h, acc[0][1]); MF(A0h, B1l, acc[0][1]); MF(A0l, B1h, acc[0][1]);
        MF(A1h, B0h, acc[1][0]); MF(A1h, B0l, acc[1][0]); MF(A1l, B0h, acc[1][0]);
        MF(A1h, B1h, acc[1][1]); MF(A1h, B1l, acc[1][1]); MF(A1l, B1h, acc[1][1]);
#undef MF
    }

    if (MODE == 0) {
        const int PP = PPH * PPW;
#pragma unroll
        for (int i = 0; i < 2; ++i)
#pragma unroll
            for (int j = 0; j < 2; ++j) {
                int p  = ptile * 16 + (wm >> 2) + i * 4 + (lane >> 4);
                int oc = n0 + wn + j * 16 + (lane & 15);
                if (p < PP) {
                    f4v v = acc[i][j];
                    float m = fmaxf(fmaxf(v.x, v.y), fmaxf(v.z, v.w));
                    m = fmaxf(m + bias[oc], 0.f);
                    out[(size_t)(b * COUT + oc) * PP + p] = m;
                }
            }
    } else {
#pragma unroll
        for (int i = 0; i < 2; ++i)
#pragma unroll
            for (int j = 0; j < 2; ++j) {
                int n = n0 + wn + j * 16 + (lane & 15);
                float bv = bias[n];
                int mb = blockIdx.x * 64 + wm + i * 16 + (lane >> 4) * 4;
                f4v v = acc[i][j];
                out[(size_t)(mb + 0) * N + n] = tanhf(v.x + bv);
                out[(size_t)(mb + 1) * N + n] = tanhf(v.y + bv);
                out[(size_t)(mb + 2) * N + n] = tanhf(v.z + bv);
                out[(size_t)(mb + 3) * N + n] = tanhf(v.w + bv);
            }
    }
}

// FC3: (128x2048) x (2048x62), K-split partials. grid=(128,KS), block=64.
__global__ __launch_bounds__(64) void k_fc3_part(
    const float* __restrict__ A, const float* __restrict__ B,
    float* __restrict__ P, int K, int N, int KS)
{
    const int m = blockIdx.x, kz = blockIdx.y;
    const int n = threadIdx.x;
    const int kchunk = K / KS;
    if (n < N) {
        float acc = 0.f;
        const float* Am = A + (size_t)m * K;
        const int ke = (kz + 1) * kchunk;
        for (int k = kz * kchunk; k < ke; ++k)
            acc = fmaf(Am[k], B[(size_t)k * N + n], acc);
        P[((size_t)kz * 128 + m) * N + n] = acc;
    }
}

__global__ void k_fc_epi(const float* __restrict__ P, const float* __restrict__ bias,
                         float* __restrict__ out, int MN, int N, int KS)
{
    int i = blockIdx.x * 256 + threadIdx.x;
    if (i >= MN) return;
    float s = 0.f;
    for (int z = 0; z < KS; ++z) s += P[(size_t)z * MN + i];
    out[i] = s + bias[i % N];
}

// Per-batch DMP segment prep (idx/amplitude/cumsum-starts). 1x128, thread = b.
__global__ void k_traj_start(const float* __restrict__ p, const float* __restrict__ td,
                             float* __restrict__ starts, float* __restrict__ sa,
                             int* __restrict__ sidx)
{
    int b = threadIdx.x;
    const float* pb = p + b * 62;
    float cx = pb[0], cy = pb[1];
    for (int s = 0; s < 20; ++s) {
        float f  = pb[2 + 3 * s];
        float a0 = pb[3 + 3 * s];
        float a1 = pb[4 + 3 * s];
        int idx = (int)fminf(fmaxf(rintf(f), 0.f), 999.f);
        int bs = b * 20 + s;
        sidx[bs] = idx;
        sa[bs * 2 + 0] = a0;
        sa[bs * 2 + 1] = a1;
        starts[bs * 2 + 0] = cx;
        starts[bs * 2 + 1] = cy;
        cx += td[((size_t)idx * 200 + 199) * 2 + 0] * a0;
        cy += td[((size_t)idx * 200 + 199) * 2 + 1] * a1;
    }
}

__global__ void k_traj_main(const float* __restrict__ td, const float* __restrict__ starts,
                            const float* __restrict__ sa, const int* __restrict__ sidx,
                            float* __restrict__ out)
{
    int bs = blockIdx.x;
    int idx = sidx[bs];
    float a0 = sa[bs * 2 + 0], a1 = sa[bs * 2 + 1];
    float s0 = starts[bs * 2 + 0], s1 = starts[bs * 2 + 1];
    const float* row = td + (size_t)idx * 400;
    float* o = out + (size_t)bs * 400;
    for (int e = threadIdx.x; e < 400; e += blockDim.x) {
        float v = row[e];
        o[e] = (e & 1) ? fmaf(v, a1, s1) : fmaf(v, a0, s0);
    }
}

// ---------------------------------------------------------------------------
extern "C" void kernel_launch(void* const* d_in, const int* in_sizes, int n_in,
                              void* d_out, int out_size, void* d_ws, size_t ws_size,
                              hipStream_t stream)
{
    (void)in_sizes; (void)n_in; (void)out_size; (void)ws_size;

    const float* x   = (const float*)d_in[0];
    const float* w1  = (const float*)d_in[1];
    const float* b1  = (const float*)d_in[2];
    const float* w2  = (const float*)d_in[3];
    const float* b2  = (const float*)d_in[4];
    const float* w3  = (const float*)d_in[5];
    const float* b3  = (const float*)d_in[6];
    const float* w4  = (const float*)d_in[7];
    const float* b4  = (const float*)d_in[8];
    const float* fw1 = (const float*)d_in[9];
    const float* fb1 = (const float*)d_in[10];
    const float* fw2 = (const float*)d_in[11];
    const float* fb2 = (const float*)d_in[12];
    const float* fw3 = (const float*)d_in[13];
    const float* fb3 = (const float*)d_in[14];
    const float* td  = (const float*)d_in[15];
    float* out = (float*)d_out;
    char* ws = (char*)d_ws;

    constexpr size_t H1 = 128ull * 64 * 49 * 49;    // conv1 out (f32 elems)
    constexpr size_t H3 = 128ull * 256 * 10 * 10;
    constexpr size_t H4 = 128ull * 512 * 16;

    // h1 [0, H1*4) ; h2 [H1*4, ...) live through conv3.
    // After conv2, h1 region is reused for h3/h4/FC buffers (all << H1*4).
    float* h1 = (float*)ws;
    float* h2 = (float*)(ws + H1 * 4);
    float* h3 = (float*)ws;
    float* h4 = (float*)(ws + H3 * 4);
    char* q = ws + (H3 + H4) * 4;
    float* part = (float*)q;          q += 4ull * 128 * 2048 * 4;
    float* a1 = (float*)q;            q += 128ull * 2048 * 4;
    float* a2 = (float*)q;            q += 128ull * 2048 * 4;
    float* p = (float*)q;             q += 128ull * 62 * 4;
    float* starts = (float*)q;        q += 128ull * 20 * 2 * 4;
    float* sa = (float*)q;            q += 128ull * 20 * 2 * 4;
    int* sidx = (int*)q;

    // conv1: 3->64, 100 -> pool 49  (direct; OCB=16 to amortize patch loads)
    k_conv_pool_relu<3, 100, 49, 16, 256, 1, 3, 64>
        <<<dim3(10, 4, 128), 256, 0, stream>>>(x, w1, b1, h1);

    // conv2: 64->128, pooled 23x23=529 -> 34 M-tiles/img, K=576
    k_gemm_mfma<0, 576, 128, 64, 49, 23, 23, 128, 34>
        <<<dim3(34 * 128, 2), 256, 0, stream>>>(h1, w2, b2, h2);
    // conv3: 128->256, pooled 10x10=100 -> 7 tiles/img, K=1152
    k_gemm_mfma<0, 1152, 256, 128, 23, 10, 10, 256, 7>
        <<<dim3(7 * 128, 4), 256, 0, stream>>>(h2, w3, b3, h3);
    // conv4: 256->512, pooled 4x4=16 -> 1 tile/img, K=2304
    k_gemm_mfma<0, 2304, 512, 256, 10, 4, 4, 512, 1>
        <<<dim3(128, 8), 256, 0, stream>>>(h3, w4, b4, h4);

    // FC1: (128x8192)x(8192x2048) + tanh   (h4 NCHW-flat == reshape order)
    k_gemm_mfma<1, 8192, 2048, 0, 1, 1, 1, 1, 1>
        <<<dim3(2, 32), 256, 0, stream>>>(h4, fw1, fb1, a1);
    // FC2: (128x2048)x(2048x2048) + tanh
    k_gemm_mfma<1, 2048, 2048, 0, 1, 1, 1, 1, 1>
        <<<dim3(2, 32), 256, 0, stream>>>(a1, fw2, fb2, a2);

    // FC3: (128x2048)x(2048x62), no act
    k_fc3_part<<<dim3(128, 4), 64, 0, stream>>>(a2, fw3, part, 2048, 62, 4);
    k_fc_epi<<<(128 * 62 + 255) / 256, 256, 0, stream>>>(
        part, fb3, p, 128 * 62, 62, 4);

    // trajectory composition
    k_traj_start<<<1, 128, 0, stream>>>(p, td, starts, sa, sidx);
    k_traj_main<<<2560, 256, 0, stream>>>(td, starts, sa, sidx, out);
}

// Round 4
// 1084.117 us; speedup vs baseline: 2.4950x; 1.3191x over previous
//
#include <hip/hip_runtime.h>
#include <hip/hip_bf16.h>

typedef __attribute__((ext_vector_type(8))) short s8v;
typedef __attribute__((ext_vector_type(4))) float f4v;
typedef unsigned short ushort;
typedef unsigned int uint;

union V8 { s8v v; short s[8]; };

__device__ __forceinline__ short f2bf(float v){
    union { __hip_bfloat16 b; short u; } x;
    x.b = __float2bfloat16(v);
    return x.u;
}
__device__ __forceinline__ float bf2f(short u){
    union { short u; __hip_bfloat16 b; } x;
    x.u = u;
    return __bfloat162float(x.b);
}
__device__ __forceinline__ void splitf(float v, short& h, short& l){
    h = f2bf(v);
    l = f2bf(v - bf2f(h));
}
__device__ __forceinline__ uint packsplit(float v){
    short h, l; splitf(v, h, l);
    return (uint)(ushort)h | ((uint)(ushort)l << 16);
}

// ---------------------------------------------------------------------------
// conv1 only (CIN=3): direct conv + pool + ReLU, writes interleaved split u32.
// ---------------------------------------------------------------------------
template<int CIN, int HIN, int PH, int OCB, int SPT, int OCS, int CICH, int COUT>
__global__ __launch_bounds__(SPT*OCS) void k_conv_pool_relu(
    const float* __restrict__ in, const float* __restrict__ w,
    const float* __restrict__ bias, uint* __restrict__ out)
{
    constexpr int BT    = SPT * OCS;
    constexpr int WIN   = HIN;
    constexpr int PW    = PH;
    constexpr int OCBLK = OCB * OCS;
    constexpr int WSTR  = CICH * 9 + 1;

    __shared__ float wsh[OCBLK * WSTR];

    const int b   = blockIdx.z;
    const int oc0 = blockIdx.y * OCBLK;
    const int t   = threadIdx.x;
    const int spl = (OCS == 1) ? t : (t % SPT);
    const int ocq = (OCS == 1) ? 0 : (t / SPT);
    const int sp  = blockIdx.x * SPT + spl;
    const bool active = sp < PH * PW;
    const int py = active ? (sp / PW) : 0;
    const int px = active ? (sp % PW) : 0;

    float acc[OCB][4];
#pragma unroll
    for (int j = 0; j < OCB; ++j)
        acc[j][0] = acc[j][1] = acc[j][2] = acc[j][3] = 0.f;

    const float* inb = in + (size_t)b * CIN * HIN * WIN;

    for (int c0 = 0; c0 < CIN; c0 += CICH) {
        __syncthreads();
        for (int i = t; i < OCBLK * CICH * 9; i += BT) {
            int j = i / (CICH * 9);
            int r = i - j * (CICH * 9);
            wsh[j * WSTR + r] = w[((size_t)(oc0 + j) * CIN + c0) * 9 + r];
        }
        __syncthreads();

        for (int ci = 0; ci < CICH; ++ci) {
            const float* inc = inb + (size_t)(c0 + ci) * HIN * WIN
                             + (2 * py) * WIN + 2 * px;
            float patch[4][4];
#pragma unroll
            for (int r = 0; r < 4; ++r)
#pragma unroll
                for (int c = 0; c < 4; ++c)
                    patch[r][c] = inc[r * WIN + c];

#pragma unroll
            for (int j = 0; j < OCB; ++j) {
                const float* wp = &wsh[(ocq * OCB + j) * WSTR + ci * 9];
#pragma unroll
                for (int kh = 0; kh < 3; ++kh)
#pragma unroll
                    for (int kw = 0; kw < 3; ++kw) {
                        float wv = wp[kh * 3 + kw];
                        acc[j][0] = fmaf(patch[kh][kw],         wv, acc[j][0]);
                        acc[j][1] = fmaf(patch[kh][kw + 1],     wv, acc[j][1]);
                        acc[j][2] = fmaf(patch[kh + 1][kw],     wv, acc[j][2]);
                        acc[j][3] = fmaf(patch[kh + 1][kw + 1], wv, acc[j][3]);
                    }
            }
        }
    }

    if (active) {
#pragma unroll
        for (int j = 0; j < OCB; ++j) {
            int oc = oc0 + ocq * OCB + j;
            float m = fmaxf(fmaxf(acc[j][0], acc[j][1]),
                            fmaxf(acc[j][2], acc[j][3]));
            m = fmaxf(m + bias[oc], 0.f);
            out[(((size_t)b * COUT + oc) * PH + py) * PW + px] = packsplit(m);
        }
    }
}

// ---------------------------------------------------------------------------
// Weight split: f32 (already [n][k]) -> hi/lo ushort planes.
// ---------------------------------------------------------------------------
__global__ void k_wsplit(const float* __restrict__ w, ushort* __restrict__ oh,
                         ushort* __restrict__ ol, int n)
{
    int i = blockIdx.x * 256 + threadIdx.x;
    if (i < n) {
        short h, l; splitf(w[i], h, l);
        oh[i] = (ushort)h; ol[i] = (ushort)l;
    }
}

// Transpose+split: f32 [K][N] -> hi/lo ushort planes [n][k]. 32x32 tiles.
__global__ __launch_bounds__(256) void k_wsplitT(
    const float* __restrict__ B, ushort* __restrict__ oh, ushort* __restrict__ ol,
    int K, int N)
{
    __shared__ float tl[32][33];
    const int n0 = blockIdx.x * 32, k0 = blockIdx.y * 32;
    const int r = threadIdx.x >> 5, c = threadIdx.x & 31;
#pragma unroll
    for (int it = 0; it < 4; ++it) {
        int row = r + it * 8;
        tl[row][c] = B[(size_t)(k0 + row) * N + n0 + c];
    }
    __syncthreads();
#pragma unroll
    for (int it = 0; it < 4; ++it) {
        int a = r + it * 8;                       // local n
        float v = tl[c][a];                       // B[k0+c][n0+a]
        short h, l; splitf(v, h, l);
        size_t o = (size_t)(n0 + a) * K + k0 + c;
        oh[o] = (ushort)h; ol[o] = (ushort)l;
    }
}

// ---------------------------------------------------------------------------
// Split-bf16 MFMA GEMM v2. Tile 64(M) x 128(N), BK=32, 4 waves (wave: 32x64).
// MODE 0: implicit-GEMM conv, A = interleaved split u32 gathered via offs[];
//         epilogue in-register 2x2 maxpool + bias + ReLU.
//         EPI 0: store interleaved split u32; EPI 1: store hi/lo planes.
// MODE 1: FC partial (grid.z = K-split): A = hi/lo ushort planes; stores f32
//         partial to O0 at [kz][m][n].
// BPRE 1: B from pre-split ushort planes [n][k]. BPRE 0: in-kernel split
//         (MODE0: f32 [n][k] vec-load; MODE1: f32 [k][n] strided).
// ---------------------------------------------------------------------------
template<int MODE, int BPRE, int EPI, int K, int KCH, int N,
         int CIN, int HIN, int PPH, int PPW, int COUT, int TPI>
__global__ __launch_bounds__(256) void k_gemm2(
    const void* __restrict__ A0, const void* __restrict__ A1,
    const void* __restrict__ B0, const void* __restrict__ B1,
    const float* __restrict__ bias, void* __restrict__ O0, void* __restrict__ O1)
{
    __shared__ short Ah[64][40], Al[64][40], Bh[128][40], Bl[128][40];
    __shared__ int offs[MODE == 0 ? K : 1];

    const int t    = threadIdx.x;
    const int lane = t & 63;
    const int wave = t >> 6;
    const int n0   = blockIdx.y * 128;
    const int sArow = t & 63, sAoct = t >> 6;
    const int sBrow = t & 127, sBo = t >> 7;

    const uint*   ArI = nullptr;
    const ushort* Ahg = nullptr;
    const ushort* Alg = nullptr;
    int b = 0, ptile = 0, kbeg = 0, kend = K;

    if (MODE == 0) {
        b = blockIdx.x / TPI;
        ptile = blockIdx.x - b * TPI;
        int pl = ptile * 16 + (sArow >> 2);
        int quad = sArow & 3;
        int py = 0, px = 0;
        if (pl < PPH * PPW) { py = pl / PPW; px = pl - py * PPW; }
        ArI = (const uint*)A0 + (size_t)b * CIN * HIN * HIN
            + (size_t)(2 * py + (quad >> 1)) * HIN + (2 * px + (quad & 1));
        for (int k = t; k < K; k += 256) {
            int ci = k / 9, r = k - ci * 9;
            int kh = r / 3, kw = r - kh * 3;
            offs[k] = ci * HIN * HIN + kh * HIN + kw;
        }
    } else {
        int arow = blockIdx.x * 64 + sArow;
        Ahg = (const ushort*)A0 + (size_t)arow * K;
        Alg = (const ushort*)A1 + (size_t)arow * K;
        kbeg = blockIdx.z * KCH;
        kend = kbeg + KCH;
    }

    f4v acc[2][4];
    const f4v z4 = {0.f, 0.f, 0.f, 0.f};
#pragma unroll
    for (int i = 0; i < 2; ++i)
#pragma unroll
        for (int j = 0; j < 4; ++j) acc[i][j] = z4;

    for (int kk = kbeg; kk < kend; kk += 32) {
        __syncthreads();   // covers offs prologue on first iter
        {   // A stage: 64 rows x 4 octets, one octet per thread
            const int kb = kk + sAoct * 8;
            V8 ha, la;
            if (MODE == 0) {
#pragma unroll
                for (int j = 0; j < 8; ++j) {
                    uint v = ArI[offs[kb + j]];
                    ha.s[j] = (short)(v & 0xffffu);
                    la.s[j] = (short)(v >> 16);
                }
            } else {
                ha.v = *(const s8v*)(Ahg + kb);
                la.v = *(const s8v*)(Alg + kb);
            }
            *(s8v*)&Ah[sArow][sAoct * 8] = ha.v;
            *(s8v*)&Al[sArow][sAoct * 8] = la.v;
        }
        {   // B stage: 128 rows x 4 octets, two octets per thread
#pragma unroll
            for (int q = 0; q < 2; ++q) {
                const int o = sBo + 2 * q;
                const int kb = kk + o * 8;
                V8 hb, lb;
                if (BPRE) {
                    hb.v = *(const s8v*)((const ushort*)B0 + (size_t)(n0 + sBrow) * K + kb);
                    lb.v = *(const s8v*)((const ushort*)B1 + (size_t)(n0 + sBrow) * K + kb);
                } else if (MODE == 0) {
                    const float* bp = (const float*)B0 + (size_t)(n0 + sBrow) * K + kb;
                    float4 v0 = *(const float4*)bp;
                    float4 v1 = *(const float4*)(bp + 4);
                    splitf(v0.x, hb.s[0], lb.s[0]); splitf(v0.y, hb.s[1], lb.s[1]);
                    splitf(v0.z, hb.s[2], lb.s[2]); splitf(v0.w, hb.s[3], lb.s[3]);
                    splitf(v1.x, hb.s[4], lb.s[4]); splitf(v1.y, hb.s[5], lb.s[5]);
                    splitf(v1.z, hb.s[6], lb.s[6]); splitf(v1.w, hb.s[7], lb.s[7]);
                } else {
                    const float* bp = (const float*)B0 + (size_t)kb * N + n0 + sBrow;
#pragma unroll
                    for (int j = 0; j < 8; ++j)
                        splitf(bp[(size_t)j * N], hb.s[j], lb.s[j]);
                }
                *(s8v*)&Bh[sBrow][o * 8] = hb.v;
                *(s8v*)&Bl[sBrow][o * 8] = lb.v;
            }
        }
        __syncthreads();

        const int fm = lane & 15;
        const int fk = (lane >> 4) * 8;
        s8v a_h[2], a_l[2], b_h[4], b_l[4];
#pragma unroll
        for (int i = 0; i < 2; ++i) {
            a_h[i] = *(const s8v*)&Ah[(wave & 1) * 32 + i * 16 + fm][fk];
            a_l[i] = *(const s8v*)&Al[(wave & 1) * 32 + i * 16 + fm][fk];
        }
#pragma unroll
        for (int j = 0; j < 4; ++j) {
            b_h[j] = *(const s8v*)&Bh[(wave >> 1) * 64 + j * 16 + fm][fk];
            b_l[j] = *(const s8v*)&Bl[(wave >> 1) * 64 + j * 16 + fm][fk];
        }
#define MF(a_, b_, c_) c_ = __builtin_amdgcn_mfma_f32_16x16x32_bf16(a_, b_, c_, 0, 0, 0)
#pragma unroll
        for (int i = 0; i < 2; ++i)
#pragma unroll
            for (int j = 0; j < 4; ++j) {
                MF(a_h[i], b_h[j], acc[i][j]);
                MF(a_h[i], b_l[j], acc[i][j]);
                MF(a_l[i], b_h[j], acc[i][j]);
            }
#undef MF
    }

    if (MODE == 0) {
        const int PP = PPH * PPW;
#pragma unroll
        for (int i = 0; i < 2; ++i)
#pragma unroll
            for (int j = 0; j < 4; ++j) {
                int p  = ptile * 16 + (wave & 1) * 8 + i * 4 + (lane >> 4);
                int oc = n0 + (wave >> 1) * 64 + j * 16 + (lane & 15);
                if (p < PP) {
                    f4v v = acc[i][j];
                    float m = fmaxf(fmaxf(v.x, v.y), fmaxf(v.z, v.w));
                    m = fmaxf(m + bias[oc], 0.f);
                    size_t o = (size_t)(b * COUT + oc) * PP + p;
                    if (EPI == 0) {
                        ((uint*)O0)[o] = packsplit(m);
                    } else {
                        short h, l; splitf(m, h, l);
                        ((ushort*)O0)[o] = (ushort)h;
                        ((ushort*)O1)[o] = (ushort)l;
                    }
                }
            }
    } else {
        float* P = (float*)O0 + (size_t)blockIdx.z * 128 * N;
#pragma unroll
        for (int i = 0; i < 2; ++i)
#pragma unroll
            for (int j = 0; j < 4; ++j) {
                int n = n0 + (wave >> 1) * 64 + j * 16 + (lane & 15);
                int mb = blockIdx.x * 64 + (wave & 1) * 32 + i * 16 + (lane >> 4) * 4;
                f4v v = acc[i][j];
                P[(size_t)(mb + 0) * N + n] = v.x;
                P[(size_t)(mb + 1) * N + n] = v.y;
                P[(size_t)(mb + 2) * N + n] = v.z;
                P[(size_t)(mb + 3) * N + n] = v.w;
            }
    }
}

// FC partial-sum epilogue: sum KS partials + bias + tanh; EFMT 1: split planes,
// EFMT 2: f32.
template<int EFMT>
__global__ void k_fc_epi2(const float* __restrict__ P, const float* __restrict__ bias,
                          ushort* __restrict__ oh, ushort* __restrict__ ol,
                          float* __restrict__ of, int MN, int N, int KS)
{
    int i = blockIdx.x * 256 + threadIdx.x;
    if (i >= MN) return;
    float s = 0.f;
    for (int z = 0; z < KS; ++z) s += P[(size_t)z * MN + i];
    s = tanhf(s + bias[i % N]);
    if (EFMT == 1) {
        short h, l; splitf(s, h, l);
        oh[i] = (ushort)h; ol[i] = (ushort)l;
    } else {
        of[i] = s;
    }
}

// FC3: (128x2048) x (2048x62) f32 vector, K-split partials.
__global__ __launch_bounds__(64) void k_fc3_part(
    const float* __restrict__ A, const float* __restrict__ B,
    float* __restrict__ P, int K, int N, int KS)
{
    const int m = blockIdx.x, kz = blockIdx.y;
    const int n = threadIdx.x;
    const int kchunk = K / KS;
    if (n < N) {
        float acc = 0.f;
        const float* Am = A + (size_t)m * K;
        const int ke = (kz + 1) * kchunk;
        for (int k = kz * kchunk; k < ke; ++k)
            acc = fmaf(Am[k], B[(size_t)k * N + n], acc);
        P[((size_t)kz * 128 + m) * N + n] = acc;
    }
}

__global__ void k_fc_epi(const float* __restrict__ P, const float* __restrict__ bias,
                         float* __restrict__ out, int MN, int N, int KS)
{
    int i = blockIdx.x * 256 + threadIdx.x;
    if (i >= MN) return;
    float s = 0.f;
    for (int z = 0; z < KS; ++z) s += P[(size_t)z * MN + i];
    out[i] = s + bias[i % N];
}

// Per-batch DMP segment prep. 1x128, thread = batch.
__global__ void k_traj_start(const float* __restrict__ p, const float* __restrict__ td,
                             float* __restrict__ starts, float* __restrict__ sa,
                             int* __restrict__ sidx)
{
    int b = threadIdx.x;
    const float* pb = p + b * 62;
    float cx = pb[0], cy = pb[1];
    for (int s = 0; s < 20; ++s) {
        float f  = pb[2 + 3 * s];
        float a0 = pb[3 + 3 * s];
        float a1 = pb[4 + 3 * s];
        int idx = (int)fminf(fmaxf(rintf(f), 0.f), 999.f);
        int bs = b * 20 + s;
        sidx[bs] = idx;
        sa[bs * 2 + 0] = a0;
        sa[bs * 2 + 1] = a1;
        starts[bs * 2 + 0] = cx;
        starts[bs * 2 + 1] = cy;
        cx += td[((size_t)idx * 200 + 199) * 2 + 0] * a0;
        cy += td[((size_t)idx * 200 + 199) * 2 + 1] * a1;
    }
}

__global__ void k_traj_main(const float* __restrict__ td, const float* __restrict__ starts,
                            const float* __restrict__ sa, const int* __restrict__ sidx,
                            float* __restrict__ out)
{
    int bs = blockIdx.x;
    int idx = sidx[bs];
    float a0 = sa[bs * 2 + 0], a1 = sa[bs * 2 + 1];
    float s0 = starts[bs * 2 + 0], s1 = starts[bs * 2 + 1];
    const float* row = td + (size_t)idx * 400;
    float* o = out + (size_t)bs * 400;
    for (int e = threadIdx.x; e < 400; e += blockDim.x) {
        float v = row[e];
        o[e] = (e & 1) ? fmaf(v, a1, s1) : fmaf(v, a0, s0);
    }
}

// ---------------------------------------------------------------------------
template<int BPRE>
static void run_all(void* const* d_in, float* out, char* ws, hipStream_t stream)
{
    const float* x   = (const float*)d_in[0];
    const float* w1  = (const float*)d_in[1];
    const float* b1  = (const float*)d_in[2];
    const float* w2  = (const float*)d_in[3];
    const float* b2  = (const float*)d_in[4];
    const float* w3  = (const float*)d_in[5];
    const float* b3  = (const float*)d_in[6];
    const float* w4  = (const float*)d_in[7];
    const float* b4  = (const float*)d_in[8];
    const float* fw1 = (const float*)d_in[9];
    const float* fb1 = (const float*)d_in[10];
    const float* fw2 = (const float*)d_in[11];
    const float* fb2 = (const float*)d_in[12];
    const float* fw3 = (const float*)d_in[13];
    const float* fb3 = (const float*)d_in[14];
    const float* td  = (const float*)d_in[15];

    // ---- workspace layout (bytes) ----
    // phase conv1-2: h1 [0, 78,675,968) u32-interleaved; h2 [78,675,968, 113,344,512)
    // after conv3 (h1,h2 dead as noted): h3, fw-splits, h4, fw2, part, a1, a2, ...
    uint*   h1   = (uint*)ws;
    uint*   h2   = (uint*)(ws + 78675968ull);
    uint*   h3   = (uint*)ws;                          // [0, 13,107,200)
    ushort* fw1h = (ushort*)(ws + 13107200ull);        // 33,554,432
    ushort* fw1l = (ushort*)(ws + 46661632ull);        // 33,554,432 (spills past h1-end; h2 head dead by then)
    ushort* h4h  = (ushort*)(ws + 80216064ull);        // 2,097,152
    ushort* h4l  = (ushort*)(ws + 82313216ull);        // 2,097,152
    ushort* fw2h = (ushort*)(ws + 84410368ull);        // 8,388,608
    ushort* fw2l = (ushort*)(ws + 92798976ull);        // 8,388,608
    float*  part = (float*)(ws + 101187584ull);        // 8 * 128*2048*4 = 8,388,608
    ushort* a1h  = (ushort*)(ws + 109576192ull);       // 524,288
    ushort* a1l  = (ushort*)(ws + 110100480ull);       // 524,288
    float*  a2   = (float*)(ws + 110624768ull);        // 1,048,576
    float*  p    = (float*)(ws + 111673344ull);
    float*  starts = (float*)(ws + 111705088ull);
    float*  sa   = (float*)(ws + 111725568ull);
    int*    sidx = (int*)(ws + 111746048ull);
    // pre-split conv weights (BPRE=1 only): disjoint tail region
    ushort* w2h = (ushort*)(ws + 113344512ull);        // 147,456
    ushort* w2l = (ushort*)(ws + 113491968ull);
    ushort* w3h = (ushort*)(ws + 113639424ull);        // 589,824
    ushort* w3l = (ushort*)(ws + 114229248ull);
    ushort* w4h = (ushort*)(ws + 114819072ull);        // 2,359,296
    ushort* w4l = (ushort*)(ws + 117178368ull);        // end 119,537,664

    if (BPRE) {
        k_wsplit<<<(73728 + 255) / 256, 256, 0, stream>>>(w2, w2h, w2l, 73728);
        k_wsplit<<<(294912 + 255) / 256, 256, 0, stream>>>(w3, w3h, w3l, 294912);
        k_wsplit<<<(1179648 + 255) / 256, 256, 0, stream>>>(w4, w4h, w4l, 1179648);
    }

    // conv1: 3->64, 100 -> pool 49 (direct)
    k_conv_pool_relu<3, 100, 49, 16, 256, 1, 3, 64>
        <<<dim3(10, 4, 128), 256, 0, stream>>>(x, w1, b1, h1);

    // conv2: 64->128, K=576, pooled 23x23 (34 M-tiles/img), N=128 (1 n-tile)
    k_gemm2<0, BPRE, 0, 576, 576, 128, 64, 49, 23, 23, 128, 34>
        <<<dim3(34 * 128, 1), 256, 0, stream>>>(
            h1, nullptr, BPRE ? (const void*)w2h : (const void*)w2,
            BPRE ? (const void*)w2l : nullptr, b2, h2, nullptr);
    // conv3: 128->256, K=1152, pooled 10x10 (7 tiles/img), N=256 (2 n-tiles)
    k_gemm2<0, BPRE, 0, 1152, 1152, 256, 128, 23, 10, 10, 256, 7>
        <<<dim3(7 * 128, 2), 256, 0, stream>>>(
            h2, nullptr, BPRE ? (const void*)w3h : (const void*)w3,
            BPRE ? (const void*)w3l : nullptr, b3, h3, nullptr);

    if (BPRE) {  // h1 (and h2 head) dead now; build FC weight planes
        k_wsplitT<<<dim3(2048 / 32, 8192 / 32), 256, 0, stream>>>(fw1, fw1h, fw1l, 8192, 2048);
        k_wsplitT<<<dim3(2048 / 32, 2048 / 32), 256, 0, stream>>>(fw2, fw2h, fw2l, 2048, 2048);
    }

    // conv4: 256->512, K=2304, pooled 4x4 (1 tile/img), N=512 (4 n-tiles) -> h4 planes
    k_gemm2<0, BPRE, 1, 2304, 2304, 512, 256, 10, 4, 4, 512, 1>
        <<<dim3(128, 4), 256, 0, stream>>>(
            h3, nullptr, BPRE ? (const void*)w4h : (const void*)w4,
            BPRE ? (const void*)w4l : nullptr, b4, h4h, h4l);

    // FC1: (128x8192)x(8192x2048), KS=8 partials + tanh -> a1 planes
    k_gemm2<1, BPRE, 2, 8192, 1024, 2048, 0, 1, 1, 1, 1, 1>
        <<<dim3(2, 16, 8), 256, 0, stream>>>(
            h4h, h4l, BPRE ? (const void*)fw1h : (const void*)fw1,
            BPRE ? (const void*)fw1l : nullptr, nullptr, part, nullptr);
    k_fc_epi2<1><<<(128 * 2048 + 255) / 256, 256, 0, stream>>>(
        part, fb1, a1h, a1l, nullptr, 128 * 2048, 2048, 8);
    // FC2: (128x2048)x(2048x2048), KS=8 partials + tanh -> a2 f32
    k_gemm2<1, BPRE, 2, 2048, 256, 2048, 0, 1, 1, 1, 1, 1>
        <<<dim3(2, 16, 8), 256, 0, stream>>>(
            a1h, a1l, BPRE ? (const void*)fw2h : (const void*)fw2,
            BPRE ? (const void*)fw2l : nullptr, nullptr, part, nullptr);
    k_fc_epi2<2><<<(128 * 2048 + 255) / 256, 256, 0, stream>>>(
        part, fb2, nullptr, nullptr, a2, 128 * 2048, 2048, 8);

    // FC3 (f32 vector) + trajectory composition
    k_fc3_part<<<dim3(128, 4), 64, 0, stream>>>(a2, fw3, part, 2048, 62, 4);
    k_fc_epi<<<(128 * 62 + 255) / 256, 256, 0, stream>>>(
        part, fb3, p, 128 * 62, 62, 4);
    k_traj_start<<<1, 128, 0, stream>>>(p, td, starts, sa, sidx);
    k_traj_main<<<2560, 256, 0, stream>>>(td, starts, sa, sidx, out);
}

extern "C" void kernel_launch(void* const* d_in, const int* in_sizes, int n_in,
                              void* d_out, int out_size, void* d_ws, size_t ws_size,
                              hipStream_t stream)
{
    (void)in_sizes; (void)n_in; (void)out_size;
    if (ws_size >= 119537664ull)
        run_all<1>(d_in, (float*)d_out, (char*)d_ws, stream);
    else
        run_all<0>(d_in, (float*)d_out, (char*)d_ws, stream);
}

// Round 5
// 1077.344 us; speedup vs baseline: 2.5107x; 1.0063x over previous
//
#include <hip/hip_runtime.h>
#include <hip/hip_bf16.h>

typedef __attribute__((ext_vector_type(8))) short s8v;
typedef __attribute__((ext_vector_type(4))) float f4v;
typedef unsigned short ushort;
typedef unsigned int uint;

union V8 { s8v v; short s[8]; };

__device__ __forceinline__ short f2bf(float v){
    union { __hip_bfloat16 b; short u; } x;
    x.b = __float2bfloat16(v);
    return x.u;
}
__device__ __forceinline__ float bf2f(short u){
    union { short u; __hip_bfloat16 b; } x;
    x.u = u;
    return __bfloat162float(x.b);
}
__device__ __forceinline__ void splitf(float v, short& h, short& l){
    h = f2bf(v);
    l = f2bf(v - bf2f(h));
}
__device__ __forceinline__ uint packsplit(float v){
    short h, l; splitf(v, h, l);
    return (uint)(ushort)h | ((uint)(ushort)l << 16);
}

// ---------------------------------------------------------------------------
// conv1 only (CIN=3): direct conv + pool + ReLU, writes interleaved split u32.
// ---------------------------------------------------------------------------
template<int CIN, int HIN, int PH, int OCB, int SPT, int OCS, int CICH, int COUT>
__global__ __launch_bounds__(SPT*OCS) void k_conv_pool_relu(
    const float* __restrict__ in, const float* __restrict__ w,
    const float* __restrict__ bias, uint* __restrict__ out)
{
    constexpr int BT    = SPT * OCS;
    constexpr int WIN   = HIN;
    constexpr int PW    = PH;
    constexpr int OCBLK = OCB * OCS;
    constexpr int WSTR  = CICH * 9 + 1;

    __shared__ float wsh[OCBLK * WSTR];

    const int b   = blockIdx.z;
    const int oc0 = blockIdx.y * OCBLK;
    const int t   = threadIdx.x;
    const int spl = (OCS == 1) ? t : (t % SPT);
    const int ocq = (OCS == 1) ? 0 : (t / SPT);
    const int sp  = blockIdx.x * SPT + spl;
    const bool active = sp < PH * PW;
    const int py = active ? (sp / PW) : 0;
    const int px = active ? (sp % PW) : 0;

    float acc[OCB][4];
#pragma unroll
    for (int j = 0; j < OCB; ++j)
        acc[j][0] = acc[j][1] = acc[j][2] = acc[j][3] = 0.f;

    const float* inb = in + (size_t)b * CIN * HIN * WIN;

    for (int c0 = 0; c0 < CIN; c0 += CICH) {
        __syncthreads();
        for (int i = t; i < OCBLK * CICH * 9; i += BT) {
            int j = i / (CICH * 9);
            int r = i - j * (CICH * 9);
            wsh[j * WSTR + r] = w[((size_t)(oc0 + j) * CIN + c0) * 9 + r];
        }
        __syncthreads();

        for (int ci = 0; ci < CICH; ++ci) {
            const float* inc = inb + (size_t)(c0 + ci) * HIN * WIN
                             + (2 * py) * WIN + 2 * px;
            float patch[4][4];
#pragma unroll
            for (int r = 0; r < 4; ++r)
#pragma unroll
                for (int c = 0; c < 4; ++c)
                    patch[r][c] = inc[r * WIN + c];

#pragma unroll
            for (int j = 0; j < OCB; ++j) {
                const float* wp = &wsh[(ocq * OCB + j) * WSTR + ci * 9];
#pragma unroll
                for (int kh = 0; kh < 3; ++kh)
#pragma unroll
                    for (int kw = 0; kw < 3; ++kw) {
                        float wv = wp[kh * 3 + kw];
                        acc[j][0] = fmaf(patch[kh][kw],         wv, acc[j][0]);
                        acc[j][1] = fmaf(patch[kh][kw + 1],     wv, acc[j][1]);
                        acc[j][2] = fmaf(patch[kh + 1][kw],     wv, acc[j][2]);
                        acc[j][3] = fmaf(patch[kh + 1][kw + 1], wv, acc[j][3]);
                    }
            }
        }
    }

    if (active) {
#pragma unroll
        for (int j = 0; j < OCB; ++j) {
            int oc = oc0 + ocq * OCB + j;
            float m = fmaxf(fmaxf(acc[j][0], acc[j][1]),
                            fmaxf(acc[j][2], acc[j][3]));
            m = fmaxf(m + bias[oc], 0.f);
            out[(((size_t)b * COUT + oc) * PH + py) * PW + px] = packsplit(m);
        }
    }
}

// ---------------------------------------------------------------------------
// Conv weight split WITH K-permutation: w[n][ci*9+r] -> planes [n][r*CIN+ci].
// ---------------------------------------------------------------------------
__global__ void k_wsplit_perm(const float* __restrict__ w, ushort* __restrict__ oh,
                              ushort* __restrict__ ol, int CIN, int total)
{
    int i = blockIdx.x * 256 + threadIdx.x;
    if (i < total) {
        int K = CIN * 9;
        int n = i / K;
        int rem = i - n * K;
        int ci = rem / 9;
        int r = rem - 9 * ci;
        short h, l; splitf(w[i], h, l);
        size_t o = (size_t)n * K + r * CIN + ci;
        oh[o] = (ushort)h; ol[o] = (ushort)l;
    }
}

// Transpose+split: f32 [K][N] -> hi/lo ushort planes [n][k]. 32x32 tiles.
__global__ __launch_bounds__(256) void k_wsplitT(
    const float* __restrict__ B, ushort* __restrict__ oh, ushort* __restrict__ ol,
    int K, int N)
{
    __shared__ float tl[32][33];
    const int n0 = blockIdx.x * 32, k0 = blockIdx.y * 32;
    const int r = threadIdx.x >> 5, c = threadIdx.x & 31;
#pragma unroll
    for (int it = 0; it < 4; ++it) {
        int row = r + it * 8;
        tl[row][c] = B[(size_t)(k0 + row) * N + n0 + c];
    }
    __syncthreads();
#pragma unroll
    for (int it = 0; it < 4; ++it) {
        int a = r + it * 8;
        float v = tl[c][a];
        short h, l; splitf(v, h, l);
        size_t o = (size_t)(n0 + a) * K + k0 + c;
        oh[o] = (ushort)h; ol[o] = (ushort)l;
    }
}

// ---------------------------------------------------------------------------
// Split-bf16 MFMA GEMM v3: reg-prefetch pipeline, permuted conv-K, no offs LDS.
// Tile 64(M) x 128(N), BK=32, 4 waves (wave: 32x64, 2x4 subtiles 16x16).
// MODE 0: implicit-GEMM conv. K-order = (kh*3+kw)*CIN + ci (ci minor, CIN pow2).
//   A = interleaved split u32, gather stride HH per element within an octet.
//   Epilogue: in-register 2x2 maxpool + bias + ReLU.
//   EPI 0: interleaved u32 out; EPI 1: hi/lo plane out.
// MODE 1: FC partial (grid.z K-split), A/B hi-lo ushort planes, f32 partial out.
// BPRE 0: in-kernel split fallback (conv: stride-9 f32 gather; FC: strided).
// ---------------------------------------------------------------------------
template<int MODE, int BPRE, int EPI, int LOG2CIN, int K, int KCH, int N,
         int HIN, int PPH, int PPW, int COUT, int TPI>
__global__ __launch_bounds__(256) void k_gemm3(
    const void* __restrict__ A0, const void* __restrict__ A1,
    const void* __restrict__ B0, const void* __restrict__ B1,
    const float* __restrict__ bias, void* __restrict__ O0, void* __restrict__ O1)
{
    constexpr int CIN = 1 << LOG2CIN;
    constexpr int HH  = HIN * HIN;

    __shared__ short Ah[64][40], Al[64][40], Bh[128][40], Bl[128][40];

    const int t    = threadIdx.x;
    const int lane = t & 63;
    const int wave = t >> 6;
    const int n0   = blockIdx.y * 128;
    const int sArow = t & 63, sAoct = t >> 6;
    const int sBrow = t & 127, sBo = t >> 7;

    const uint*   ArI = nullptr;
    const ushort* Ahg = nullptr;
    const ushort* Alg = nullptr;
    int b = 0, ptile = 0, kbeg = 0, kend = K;

    if (MODE == 0) {
        b = blockIdx.x / TPI;
        ptile = blockIdx.x - b * TPI;
        int pl = ptile * 16 + (sArow >> 2);
        int quad = sArow & 3;
        int py = 0, px = 0;
        if (pl < PPH * PPW) { py = pl / PPW; px = pl - py * PPW; }
        ArI = (const uint*)A0 + (size_t)b * CIN * HH
            + (size_t)(2 * py + (quad >> 1)) * HIN + (2 * px + (quad & 1));
    } else {
        int arow = blockIdx.x * 64 + sArow;
        Ahg = (const ushort*)A0 + (size_t)arow * K;
        Alg = (const ushort*)A1 + (size_t)arow * K;
        kbeg = blockIdx.z * KCH;
        kend = kbeg + KCH;
    }

    // ---- prefetch helpers ----
    auto pfA = [&](int kkx, V8& ha, V8& la) {
        const int kb = kkx + sAoct * 8;
        if (MODE == 0) {
            const int r  = kb >> LOG2CIN;       // fixed across the octet
            const int cb = kb & (CIN - 1);
            const int rh = (r * 11) >> 5;       // r/3 for r<9
            const int rw = r - 3 * rh;
            const uint* g = ArI + (size_t)cb * HH + rh * HIN + rw;
#pragma unroll
            for (int j = 0; j < 8; ++j) {
                uint v = g[(size_t)j * HH];
                ha.s[j] = (short)(v & 0xffffu);
                la.s[j] = (short)(v >> 16);
            }
        } else {
            ha.v = *(const s8v*)(Ahg + kb);
            la.v = *(const s8v*)(Alg + kb);
        }
    };
    auto pfB = [&](int kkx, V8* hb, V8* lb) {
#pragma unroll
        for (int q = 0; q < 2; ++q) {
            const int o = sBo + 2 * q;
            const int kb = kkx + o * 8;
            if (BPRE) {
                hb[q].v = *(const s8v*)((const ushort*)B0 + (size_t)(n0 + sBrow) * K + kb);
                lb[q].v = *(const s8v*)((const ushort*)B1 + (size_t)(n0 + sBrow) * K + kb);
            } else if (MODE == 0) {
                // fallback: permuted gather from f32 w[n][ci*9+r], stride 9
                const int r  = kb >> LOG2CIN;
                const int cb = kb & (CIN - 1);
                const float* bp = (const float*)B0
                    + (size_t)(n0 + sBrow) * K + (size_t)cb * 9 + r;
#pragma unroll
                for (int j = 0; j < 8; ++j)
                    splitf(bp[9 * j], hb[q].s[j], lb[q].s[j]);
            } else {
                const float* bp = (const float*)B0 + (size_t)kb * N + n0 + sBrow;
#pragma unroll
                for (int j = 0; j < 8; ++j)
                    splitf(bp[(size_t)j * N], hb[q].s[j], lb[q].s[j]);
            }
        }
    };

    f4v acc[2][4];
    const f4v z4 = {0.f, 0.f, 0.f, 0.f};
#pragma unroll
    for (int i = 0; i < 2; ++i)
#pragma unroll
        for (int j = 0; j < 4; ++j) acc[i][j] = z4;

    V8 pAh, pAl, pBh[2], pBl[2];
    pfA(kbeg, pAh, pAl);
    pfB(kbeg, pBh, pBl);

    for (int kk = kbeg; kk < kend; kk += 32) {
        __syncthreads();                       // prev iter's frag reads done
        *(s8v*)&Ah[sArow][sAoct * 8] = pAh.v;
        *(s8v*)&Al[sArow][sAoct * 8] = pAl.v;
#pragma unroll
        for (int q = 0; q < 2; ++q) {
            const int o = sBo + 2 * q;
            *(s8v*)&Bh[sBrow][o * 8] = pBh[q].v;
            *(s8v*)&Bl[sBrow][o * 8] = pBl[q].v;
        }
        if (kk + 32 < kend) {                  // issue next tile's loads now;
            pfA(kk + 32, pAh, pAl);            // they overlap MFMA below
            pfB(kk + 32, pBh, pBl);
        }
        __syncthreads();                       // LDS tile visible

        const int fm = lane & 15;
        const int fk = (lane >> 4) * 8;
        s8v a_h[2], a_l[2], b_h[4], b_l[4];
#pragma unroll
        for (int i = 0; i < 2; ++i) {
            a_h[i] = *(const s8v*)&Ah[(wave & 1) * 32 + i * 16 + fm][fk];
            a_l[i] = *(const s8v*)&Al[(wave & 1) * 32 + i * 16 + fm][fk];
        }
#pragma unroll
        for (int j = 0; j < 4; ++j) {
            b_h[j] = *(const s8v*)&Bh[(wave >> 1) * 64 + j * 16 + fm][fk];
            b_l[j] = *(const s8v*)&Bl[(wave >> 1) * 64 + j * 16 + fm][fk];
        }
#define MF(a_, b_, c_) c_ = __builtin_amdgcn_mfma_f32_16x16x32_bf16(a_, b_, c_, 0, 0, 0)
#pragma unroll
        for (int i = 0; i < 2; ++i)
#pragma unroll
            for (int j = 0; j < 4; ++j) {
                MF(a_h[i], b_h[j], acc[i][j]);
                MF(a_h[i], b_l[j], acc[i][j]);
                MF(a_l[i], b_h[j], acc[i][j]);
            }
#undef MF
    }

    if (MODE == 0) {
        const int PP = PPH * PPW;
#pragma unroll
        for (int i = 0; i < 2; ++i)
#pragma unroll
            for (int j = 0; j < 4; ++j) {
                int p  = ptile * 16 + (wave & 1) * 8 + i * 4 + (lane >> 4);
                int oc = n0 + (wave >> 1) * 64 + j * 16 + (lane & 15);
                if (p < PP) {
                    f4v v = acc[i][j];
                    float m = fmaxf(fmaxf(v.x, v.y), fmaxf(v.z, v.w));
                    m = fmaxf(m + bias[oc], 0.f);
                    size_t o = (size_t)(b * COUT + oc) * PP + p;
                    if (EPI == 0) {
                        ((uint*)O0)[o] = packsplit(m);
                    } else {
                        short h, l; splitf(m, h, l);
                        ((ushort*)O0)[o] = (ushort)h;
                        ((ushort*)O1)[o] = (ushort)l;
                    }
                }
            }
    } else {
        float* P = (float*)O0 + (size_t)blockIdx.z * 128 * N;
#pragma unroll
        for (int i = 0; i < 2; ++i)
#pragma unroll
            for (int j = 0; j < 4; ++j) {
                int n = n0 + (wave >> 1) * 64 + j * 16 + (lane & 15);
                int mb = blockIdx.x * 64 + (wave & 1) * 32 + i * 16 + (lane >> 4) * 4;
                f4v v = acc[i][j];
                P[(size_t)(mb + 0) * N + n] = v.x;
                P[(size_t)(mb + 1) * N + n] = v.y;
                P[(size_t)(mb + 2) * N + n] = v.z;
                P[(size_t)(mb + 3) * N + n] = v.w;
            }
    }
}

// FC partial-sum epilogue: sum KS partials + bias + tanh; EFMT 1: split planes,
// EFMT 2: f32.
template<int EFMT>
__global__ void k_fc_epi2(const float* __restrict__ P, const float* __restrict__ bias,
                          ushort* __restrict__ oh, ushort* __restrict__ ol,
                          float* __restrict__ of, int MN, int N, int KS)
{
    int i = blockIdx.x * 256 + threadIdx.x;
    if (i >= MN) return;
    float s = 0.f;
    for (int z = 0; z < KS; ++z) s += P[(size_t)z * MN + i];
    s = tanhf(s + bias[i % N]);
    if (EFMT == 1) {
        short h, l; splitf(s, h, l);
        oh[i] = (ushort)h; ol[i] = (ushort)l;
    } else {
        of[i] = s;
    }
}

// FC3: (128x2048) x (2048x62) f32 vector, K-split partials.
__global__ __launch_bounds__(64) void k_fc3_part(
    const float* __restrict__ A, const float* __restrict__ B,
    float* __restrict__ P, int K, int N, int KS)
{
    const int m = blockIdx.x, kz = blockIdx.y;
    const int n = threadIdx.x;
    const int kchunk = K / KS;
    if (n < N) {
        float acc = 0.f;
        const float* Am = A + (size_t)m * K;
        const int ke = (kz + 1) * kchunk;
        for (int k = kz * kchunk; k < ke; ++k)
            acc = fmaf(Am[k], B[(size_t)k * N + n], acc);
        P[((size_t)kz * 128 + m) * N + n] = acc;
    }
}

__global__ void k_fc_epi(const float* __restrict__ P, const float* __restrict__ bias,
                         float* __restrict__ out, int MN, int N, int KS)
{
    int i = blockIdx.x * 256 + threadIdx.x;
    if (i >= MN) return;
    float s = 0.f;
    for (int z = 0; z < KS; ++z) s += P[(size_t)z * MN + i];
    out[i] = s + bias[i % N];
}

// Per-batch DMP segment prep. 1x128, thread = batch.
__global__ void k_traj_start(const float* __restrict__ p, const float* __restrict__ td,
                             float* __restrict__ starts, float* __restrict__ sa,
                             int* __restrict__ sidx)
{
    int b = threadIdx.x;
    const float* pb = p + b * 62;
    float cx = pb[0], cy = pb[1];
    for (int s = 0; s < 20; ++s) {
        float f  = pb[2 + 3 * s];
        float a0 = pb[3 + 3 * s];
        float a1 = pb[4 + 3 * s];
        int idx = (int)fminf(fmaxf(rintf(f), 0.f), 999.f);
        int bs = b * 20 + s;
        sidx[bs] = idx;
        sa[bs * 2 + 0] = a0;
        sa[bs * 2 + 1] = a1;
        starts[bs * 2 + 0] = cx;
        starts[bs * 2 + 1] = cy;
        cx += td[((size_t)idx * 200 + 199) * 2 + 0] * a0;
        cy += td[((size_t)idx * 200 + 199) * 2 + 1] * a1;
    }
}

__global__ void k_traj_main(const float* __restrict__ td, const float* __restrict__ starts,
                            const float* __restrict__ sa, const int* __restrict__ sidx,
                            float* __restrict__ out)
{
    int bs = blockIdx.x;
    int idx = sidx[bs];
    float a0 = sa[bs * 2 + 0], a1 = sa[bs * 2 + 1];
    float s0 = starts[bs * 2 + 0], s1 = starts[bs * 2 + 1];
    const float* row = td + (size_t)idx * 400;
    float* o = out + (size_t)bs * 400;
    for (int e = threadIdx.x; e < 400; e += blockDim.x) {
        float v = row[e];
        o[e] = (e & 1) ? fmaf(v, a1, s1) : fmaf(v, a0, s0);
    }
}

// ---------------------------------------------------------------------------
template<int BPRE>
static void run_all(void* const* d_in, float* out, char* ws, hipStream_t stream)
{
    const float* x   = (const float*)d_in[0];
    const float* w1  = (const float*)d_in[1];
    const float* b1  = (const float*)d_in[2];
    const float* w2  = (const float*)d_in[3];
    const float* b2  = (const float*)d_in[4];
    const float* w3  = (const float*)d_in[5];
    const float* b3  = (const float*)d_in[6];
    const float* w4  = (const float*)d_in[7];
    const float* b4  = (const float*)d_in[8];
    const float* fw1 = (const float*)d_in[9];
    const float* fb1 = (const float*)d_in[10];
    const float* fw2 = (const float*)d_in[11];
    const float* fb2 = (const float*)d_in[12];
    const float* fw3 = (const float*)d_in[13];
    const float* fb3 = (const float*)d_in[14];
    const float* td  = (const float*)d_in[15];

    // ---- workspace layout (bytes) ----
    uint*   h1   = (uint*)ws;                          // [0, 78,675,968)
    uint*   h2   = (uint*)(ws + 78675968ull);          // 34,668,544
    uint*   h3   = (uint*)ws;                          // [0, 13,107,200)
    ushort* fw1h = (ushort*)(ws + 13107200ull);        // 33,554,432
    ushort* fw1l = (ushort*)(ws + 46661632ull);        // 33,554,432
    ushort* h4h  = (ushort*)(ws + 80216064ull);        // 2,097,152
    ushort* h4l  = (ushort*)(ws + 82313216ull);        // 2,097,152
    ushort* fw2h = (ushort*)(ws + 84410368ull);        // 8,388,608
    ushort* fw2l = (ushort*)(ws + 92798976ull);        // 8,388,608
    float*  part = (float*)(ws + 101187584ull);        // 8,388,608
    ushort* a1h  = (ushort*)(ws + 109576192ull);       // 524,288
    ushort* a1l  = (ushort*)(ws + 110100480ull);       // 524,288
    float*  a2   = (float*)(ws + 110624768ull);        // 1,048,576
    float*  p    = (float*)(ws + 111673344ull);
    float*  starts = (float*)(ws + 111705088ull);
    float*  sa   = (float*)(ws + 111725568ull);
    int*    sidx = (int*)(ws + 111746048ull);
    ushort* w2h = (ushort*)(ws + 113344512ull);
    ushort* w2l = (ushort*)(ws + 113491968ull);
    ushort* w3h = (ushort*)(ws + 113639424ull);
    ushort* w3l = (ushort*)(ws + 114229248ull);
    ushort* w4h = (ushort*)(ws + 114819072ull);
    ushort* w4l = (ushort*)(ws + 117178368ull);        // end 119,537,664

    if (BPRE) {   // permuted split: [n][ci*9+r] -> [n][r*CIN+ci]
        k_wsplit_perm<<<(73728 + 255) / 256, 256, 0, stream>>>(w2, w2h, w2l, 64, 73728);
        k_wsplit_perm<<<(294912 + 255) / 256, 256, 0, stream>>>(w3, w3h, w3l, 128, 294912);
        k_wsplit_perm<<<(1179648 + 255) / 256, 256, 0, stream>>>(w4, w4h, w4l, 256, 1179648);
    }

    // conv1: 3->64, 100 -> pool 49 (direct)
    k_conv_pool_relu<3, 100, 49, 16, 256, 1, 3, 64>
        <<<dim3(10, 4, 128), 256, 0, stream>>>(x, w1, b1, h1);

    // conv2: 64->128, K=576, pooled 23x23 (34 M-tiles/img), N=128
    k_gemm3<0, BPRE, 0, 6, 576, 576, 128, 49, 23, 23, 128, 34>
        <<<dim3(34 * 128, 1), 256, 0, stream>>>(
            h1, nullptr, BPRE ? (const void*)w2h : (const void*)w2,
            BPRE ? (const void*)w2l : nullptr, b2, h2, nullptr);
    // conv3: 128->256, K=1152, pooled 10x10 (7 tiles/img), N=256
    k_gemm3<0, BPRE, 0, 7, 1152, 1152, 256, 23, 10, 10, 256, 7>
        <<<dim3(7 * 128, 2), 256, 0, stream>>>(
            h2, nullptr, BPRE ? (const void*)w3h : (const void*)w3,
            BPRE ? (const void*)w3l : nullptr, b3, h3, nullptr);

    if (BPRE) {   // h1/h2-head dead; build FC weight planes
        k_wsplitT<<<dim3(2048 / 32, 8192 / 32), 256, 0, stream>>>(fw1, fw1h, fw1l, 8192, 2048);
        k_wsplitT<<<dim3(2048 / 32, 2048 / 32), 256, 0, stream>>>(fw2, fw2h, fw2l, 2048, 2048);
    }

    // conv4: 256->512, K=2304, pooled 4x4 (1 tile/img), N=512 -> h4 planes
    k_gemm3<0, BPRE, 1, 8, 2304, 2304, 512, 10, 4, 4, 512, 1>
        <<<dim3(128, 4), 256, 0, stream>>>(
            h3, nullptr, BPRE ? (const void*)w4h : (const void*)w4,
            BPRE ? (const void*)w4l : nullptr, b4, h4h, h4l);

    // FC1: (128x8192)x(8192x2048), KS=8 partials + tanh -> a1 planes
    k_gemm3<1, BPRE, 2, 0, 8192, 1024, 2048, 1, 1, 1, 1, 1>
        <<<dim3(2, 16, 8), 256, 0, stream>>>(
            h4h, h4l, BPRE ? (const void*)fw1h : (const void*)fw1,
            BPRE ? (const void*)fw1l : nullptr, nullptr, part, nullptr);
    k_fc_epi2<1><<<(128 * 2048 + 255) / 256, 256, 0, stream>>>(
        part, fb1, a1h, a1l, nullptr, 128 * 2048, 2048, 8);
    // FC2: (128x2048)x(2048x2048), KS=8 partials + tanh -> a2 f32
    k_gemm3<1, BPRE, 2, 0, 2048, 256, 2048, 1, 1, 1, 1, 1>
        <<<dim3(2, 16, 8), 256, 0, stream>>>(
            a1h, a1l, BPRE ? (const void*)fw2h : (const void*)fw2,
            BPRE ? (const void*)fw2l : nullptr, nullptr, part, nullptr);
    k_fc_epi2<2><<<(128 * 2048 + 255) / 256, 256, 0, stream>>>(
        part, fb2, nullptr, nullptr, a2, 128 * 2048, 2048, 8);

    // FC3 (f32 vector) + trajectory composition
    k_fc3_part<<<dim3(128, 4), 64, 0, stream>>>(a2, fw3, part, 2048, 62, 4);
    k_fc_epi<<<(128 * 62 + 255) / 256, 256, 0, stream>>>(
        part, fb3, p, 128 * 62, 62, 4);
    k_traj_start<<<1, 128, 0, stream>>>(p, td, starts, sa, sidx);
    k_traj_main<<<2560, 256, 0, stream>>>(td, starts, sa, sidx, out);
}

extern "C" void kernel_launch(void* const* d_in, const int* in_sizes, int n_in,
                              void* d_out, int out_size, void* d_ws, size_t ws_size,
                              hipStream_t stream)
{
    (void)in_sizes; (void)n_in; (void)out_size;
    if (ws_size >= 119537664ull)
        run_all<1>(d_in, (float*)d_out, (char*)d_ws, stream);
    else
        run_all<0>(d_in, (float*)d_out, (char*)d_ws, stream);
}

// Round 6
// 1045.076 us; speedup vs baseline: 2.5882x; 1.0309x over previous
//
#include <hip/hip_runtime.h>
#include <hip/hip_bf16.h>

typedef __attribute__((ext_vector_type(8))) short s8v;
typedef __attribute__((ext_vector_type(4))) float f4v;
typedef unsigned short ushort;
typedef unsigned int uint;

union V8 { s8v v; short s[8]; };

__device__ __forceinline__ short f2bf(float v){
    union { __hip_bfloat16 b; short u; } x;
    x.b = __float2bfloat16(v);
    return x.u;
}
__device__ __forceinline__ float bf2f(short u){
    union { short u; __hip_bfloat16 b; } x;
    x.u = u;
    return __bfloat162float(x.b);
}
__device__ __forceinline__ void splitf(float v, short& h, short& l){
    h = f2bf(v);
    l = f2bf(v - bf2f(h));
}
__device__ __forceinline__ uint packsplit(float v){
    short h, l; splitf(v, h, l);
    return (uint)(ushort)h | ((uint)(ushort)l << 16);
}

// ---------------------------------------------------------------------------
// conv1 (CIN=3): direct conv + pool + ReLU -> NHWC interleaved-split u32.
// OCS==1 path only; OCB consecutive oc per thread -> uint4 stores.
// ---------------------------------------------------------------------------
template<int CIN, int HIN, int PH, int OCB, int SPT, int CICH, int COUT>
__global__ __launch_bounds__(SPT) void k_conv_pool_relu(
    const float* __restrict__ in, const float* __restrict__ w,
    const float* __restrict__ bias, uint* __restrict__ out)
{
    constexpr int WIN   = HIN;
    constexpr int PW    = PH;
    constexpr int WSTR  = CICH * 9 + 1;

    __shared__ float wsh[OCB * WSTR];

    const int b   = blockIdx.z;
    const int oc0 = blockIdx.y * OCB;
    const int t   = threadIdx.x;
    const int sp  = blockIdx.x * SPT + t;
    const bool active = sp < PH * PW;
    const int py = active ? (sp / PW) : 0;
    const int px = active ? (sp % PW) : 0;

    float acc[OCB][4];
#pragma unroll
    for (int j = 0; j < OCB; ++j)
        acc[j][0] = acc[j][1] = acc[j][2] = acc[j][3] = 0.f;

    const float* inb = in + (size_t)b * CIN * HIN * WIN;

    for (int c0 = 0; c0 < CIN; c0 += CICH) {
        __syncthreads();
        for (int i = t; i < OCB * CICH * 9; i += SPT) {
            int j = i / (CICH * 9);
            int r = i - j * (CICH * 9);
            wsh[j * WSTR + r] = w[((size_t)(oc0 + j) * CIN + c0) * 9 + r];
        }
        __syncthreads();

        for (int ci = 0; ci < CICH; ++ci) {
            const float* inc = inb + (size_t)(c0 + ci) * HIN * WIN
                             + (2 * py) * WIN + 2 * px;
            float patch[4][4];
#pragma unroll
            for (int r = 0; r < 4; ++r)
#pragma unroll
                for (int c = 0; c < 4; ++c)
                    patch[r][c] = inc[r * WIN + c];

#pragma unroll
            for (int j = 0; j < OCB; ++j) {
                const float* wp = &wsh[j * WSTR + ci * 9];
#pragma unroll
                for (int kh = 0; kh < 3; ++kh)
#pragma unroll
                    for (int kw = 0; kw < 3; ++kw) {
                        float wv = wp[kh * 3 + kw];
                        acc[j][0] = fmaf(patch[kh][kw],         wv, acc[j][0]);
                        acc[j][1] = fmaf(patch[kh][kw + 1],     wv, acc[j][1]);
                        acc[j][2] = fmaf(patch[kh + 1][kw],     wv, acc[j][2]);
                        acc[j][3] = fmaf(patch[kh + 1][kw + 1], wv, acc[j][3]);
                    }
            }
        }
    }

    if (active) {
        uint tmp[OCB];
#pragma unroll
        for (int j = 0; j < OCB; ++j) {
            float m = fmaxf(fmaxf(acc[j][0], acc[j][1]),
                            fmaxf(acc[j][2], acc[j][3]));
            m = fmaxf(m + bias[oc0 + j], 0.f);
            tmp[j] = packsplit(m);
        }
        // NHWC: [b][p][oc]
        uint* ob = out + ((size_t)b * PH * PW + sp) * COUT + oc0;
#pragma unroll
        for (int q = 0; q < OCB / 4; ++q)
            ((uint4*)ob)[q] = ((const uint4*)tmp)[q];
    }
}

// ---------------------------------------------------------------------------
// Conv weight split WITH K-permutation: w[n][ci*9+r] -> planes [n][r*CIN+ci].
// ---------------------------------------------------------------------------
__global__ void k_wsplit_perm(const float* __restrict__ w, ushort* __restrict__ oh,
                              ushort* __restrict__ ol, int CIN, int total)
{
    int i = blockIdx.x * 256 + threadIdx.x;
    if (i < total) {
        int K = CIN * 9;
        int n = i / K;
        int rem = i - n * K;
        int ci = rem / 9;
        int r = rem - 9 * ci;
        short h, l; splitf(w[i], h, l);
        size_t o = (size_t)n * K + r * CIN + ci;
        oh[o] = (ushort)h; ol[o] = (ushort)l;
    }
}

// Transpose+split: f32 [K][N] -> hi/lo ushort planes [n][k]. 32x32 tiles.
__global__ __launch_bounds__(256) void k_wsplitT(
    const float* __restrict__ B, ushort* __restrict__ oh, ushort* __restrict__ ol,
    int K, int N)
{
    __shared__ float tl[32][33];
    const int n0 = blockIdx.x * 32, k0 = blockIdx.y * 32;
    const int r = threadIdx.x >> 5, c = threadIdx.x & 31;
#pragma unroll
    for (int it = 0; it < 4; ++it) {
        int row = r + it * 8;
        tl[row][c] = B[(size_t)(k0 + row) * N + n0 + c];
    }
    __syncthreads();
#pragma unroll
    for (int it = 0; it < 4; ++it) {
        int a = r + it * 8;
        float v = tl[c][a];
        short h, l; splitf(v, h, l);
        size_t o = (size_t)(n0 + a) * K + k0 + c;
        oh[o] = (ushort)h; ol[o] = (ushort)l;
    }
}

// ---------------------------------------------------------------------------
// Split-bf16 MFMA GEMM v4: NHWC activations -> contiguous 32B A-octets.
// Tile 64(M) x 128(N), BK=32, 4 waves (wave: 32x64, 2x4 subtiles 16x16).
// MODE 0: implicit-GEMM conv. K-order = (kh*3+kw)*CIN + ci.
//   A = NHWC interleaved-split u32: octet = 8 consecutive ci at one spatial
//   position -> 2x dwordx4. Epilogue: in-register 2x2 maxpool + bias + ReLU.
//   EPI 0: NHWC interleaved u32 out; EPI 1: NCHW hi/lo plane out (for FC1).
// MODE 1: FC partial (grid.z K-split), A/B hi-lo ushort planes, f32 partials.
// BPRE 0: in-kernel B split fallback.
// ---------------------------------------------------------------------------
template<int MODE, int BPRE, int EPI, int LOG2CIN, int K, int KCH, int N,
         int HIN, int PPH, int PPW, int COUT, int TPI>
__global__ __launch_bounds__(256) void k_gemm4(
    const void* __restrict__ A0, const void* __restrict__ A1,
    const void* __restrict__ B0, const void* __restrict__ B1,
    const float* __restrict__ bias, void* __restrict__ O0, void* __restrict__ O1)
{
    constexpr int CIN = 1 << LOG2CIN;
    constexpr int HH  = HIN * HIN;

    __shared__ short Ah[64][40], Al[64][40], Bh[128][40], Bl[128][40];

    const int t    = threadIdx.x;
    const int lane = t & 63;
    const int wave = t >> 6;
    const int n0   = blockIdx.y * 128;
    const int sArow = t & 63, sAoct = t >> 6;
    const int sBrow = t & 127, sBo = t >> 7;

    const uint*   ArI = nullptr;   // NHWC base at (b, y0, x0, 0)
    const ushort* Ahg = nullptr;
    const ushort* Alg = nullptr;
    int b = 0, ptile = 0, kbeg = 0, kend = K;

    if (MODE == 0) {
        b = blockIdx.x / TPI;
        ptile = blockIdx.x - b * TPI;
        int pl = ptile * 16 + (sArow >> 2);
        int quad = sArow & 3;
        int py = 0, px = 0;
        if (pl < PPH * PPW) { py = pl / PPW; px = pl - py * PPW; }
        ArI = (const uint*)A0
            + ((size_t)b * HH + (size_t)(2 * py + (quad >> 1)) * HIN
               + (2 * px + (quad & 1))) * CIN;
    } else {
        int arow = blockIdx.x * 64 + sArow;
        Ahg = (const ushort*)A0 + (size_t)arow * K;
        Alg = (const ushort*)A1 + (size_t)arow * K;
        kbeg = blockIdx.z * KCH;
        kend = kbeg + KCH;
    }

    // ---- prefetch helpers ----
    auto pfA = [&](int kkx, V8& ha, V8& la) {
        const int kb = kkx + sAoct * 8;
        if (MODE == 0) {
            const int r  = kb >> LOG2CIN;       // wave-uniform
            const int cb = kb & (CIN - 1);      // wave-uniform, multiple of 8
            const int rh = (r * 11) >> 5;       // r/3 for r<9
            const int rw = r - 3 * rh;
            const uint* g = ArI + (rh * HIN + rw) * CIN + cb;  // 32B contiguous
            uint4 v0 = *(const uint4*)g;
            uint4 v1 = *(const uint4*)(g + 4);
            uint vv[8] = {v0.x, v0.y, v0.z, v0.w, v1.x, v1.y, v1.z, v1.w};
#pragma unroll
            for (int j = 0; j < 8; ++j) {
                ha.s[j] = (short)(vv[j] & 0xffffu);
                la.s[j] = (short)(vv[j] >> 16);
            }
        } else {
            ha.v = *(const s8v*)(Ahg + kb);
            la.v = *(const s8v*)(Alg + kb);
        }
    };
    auto pfB = [&](int kkx, V8* hb, V8* lb) {
#pragma unroll
        for (int q = 0; q < 2; ++q) {
            const int o = sBo + 2 * q;
            const int kb = kkx + o * 8;
            if (BPRE) {
                hb[q].v = *(const s8v*)((const ushort*)B0 + (size_t)(n0 + sBrow) * K + kb);
                lb[q].v = *(const s8v*)((const ushort*)B1 + (size_t)(n0 + sBrow) * K + kb);
            } else if (MODE == 0) {
                // fallback: permuted gather from f32 w[n][ci*9+r], stride 9
                const int r  = kb >> LOG2CIN;
                const int cb = kb & (CIN - 1);
                const float* bp = (const float*)B0
                    + (size_t)(n0 + sBrow) * K + (size_t)cb * 9 + r;
#pragma unroll
                for (int j = 0; j < 8; ++j)
                    splitf(bp[9 * j], hb[q].s[j], lb[q].s[j]);
            } else {
                const float* bp = (const float*)B0 + (size_t)kb * N + n0 + sBrow;
#pragma unroll
                for (int j = 0; j < 8; ++j)
                    splitf(bp[(size_t)j * N], hb[q].s[j], lb[q].s[j]);
            }
        }
    };

    f4v acc[2][4];
    const f4v z4 = {0.f, 0.f, 0.f, 0.f};
#pragma unroll
    for (int i = 0; i < 2; ++i)
#pragma unroll
        for (int j = 0; j < 4; ++j) acc[i][j] = z4;

    V8 pAh, pAl, pBh[2], pBl[2];
    pfA(kbeg, pAh, pAl);
    pfB(kbeg, pBh, pBl);

    for (int kk = kbeg; kk < kend; kk += 32) {
        __syncthreads();                       // prev iter's frag reads done
        *(s8v*)&Ah[sArow][sAoct * 8] = pAh.v;
        *(s8v*)&Al[sArow][sAoct * 8] = pAl.v;
#pragma unroll
        for (int q = 0; q < 2; ++q) {
            const int o = sBo + 2 * q;
            *(s8v*)&Bh[sBrow][o * 8] = pBh[q].v;
            *(s8v*)&Bl[sBrow][o * 8] = pBl[q].v;
        }
        if (kk + 32 < kend) {                  // overlap next loads with MFMA
            pfA(kk + 32, pAh, pAl);
            pfB(kk + 32, pBh, pBl);
        }
        __syncthreads();                       // LDS tile visible

        const int fm = lane & 15;
        const int fk = (lane >> 4) * 8;
        s8v a_h[2], a_l[2], b_h[4], b_l[4];
#pragma unroll
        for (int i = 0; i < 2; ++i) {
            a_h[i] = *(const s8v*)&Ah[(wave & 1) * 32 + i * 16 + fm][fk];
            a_l[i] = *(const s8v*)&Al[(wave & 1) * 32 + i * 16 + fm][fk];
        }
#pragma unroll
        for (int j = 0; j < 4; ++j) {
            b_h[j] = *(const s8v*)&Bh[(wave >> 1) * 64 + j * 16 + fm][fk];
            b_l[j] = *(const s8v*)&Bl[(wave >> 1) * 64 + j * 16 + fm][fk];
        }
#define MF(a_, b_, c_) c_ = __builtin_amdgcn_mfma_f32_16x16x32_bf16(a_, b_, c_, 0, 0, 0)
#pragma unroll
        for (int i = 0; i < 2; ++i)
#pragma unroll
            for (int j = 0; j < 4; ++j) {
                MF(a_h[i], b_h[j], acc[i][j]);
                MF(a_h[i], b_l[j], acc[i][j]);
                MF(a_l[i], b_h[j], acc[i][j]);
            }
#undef MF
    }

    if (MODE == 0) {
        const int PP = PPH * PPW;
#pragma unroll
        for (int i = 0; i < 2; ++i)
#pragma unroll
            for (int j = 0; j < 4; ++j) {
                int p  = ptile * 16 + (wave & 1) * 8 + i * 4 + (lane >> 4);
                int oc = n0 + (wave >> 1) * 64 + j * 16 + (lane & 15);
                if (p < PP) {
                    f4v v = acc[i][j];
                    float m = fmaxf(fmaxf(v.x, v.y), fmaxf(v.z, v.w));
                    m = fmaxf(m + bias[oc], 0.f);
                    if (EPI == 0) {
                        // NHWC interleaved u32 (consecutive oc per lane-group)
                        ((uint*)O0)[((size_t)b * PP + p) * COUT + oc] = packsplit(m);
                    } else {
                        // NCHW hi/lo planes (FC1 A layout)
                        size_t o = (size_t)(b * COUT + oc) * PP + p;
                        short h, l; splitf(m, h, l);
                        ((ushort*)O0)[o] = (ushort)h;
                        ((ushort*)O1)[o] = (ushort)l;
                    }
                }
            }
    } else {
        float* P = (float*)O0 + (size_t)blockIdx.z * 128 * N;
#pragma unroll
        for (int i = 0; i < 2; ++i)
#pragma unroll
            for (int j = 0; j < 4; ++j) {
                int n = n0 + (wave >> 1) * 64 + j * 16 + (lane & 15);
                int mb = blockIdx.x * 64 + (wave & 1) * 32 + i * 16 + (lane >> 4) * 4;
                f4v v = acc[i][j];
                P[(size_t)(mb + 0) * N + n] = v.x;
                P[(size_t)(mb + 1) * N + n] = v.y;
                P[(size_t)(mb + 2) * N + n] = v.z;
                P[(size_t)(mb + 3) * N + n] = v.w;
            }
    }
}

// FC partial-sum epilogue: sum KS partials + bias + tanh; EFMT 1: split planes,
// EFMT 2: f32.
template<int EFMT>
__global__ void k_fc_epi2(const float* __restrict__ P, const float* __restrict__ bias,
                          ushort* __restrict__ oh, ushort* __restrict__ ol,
                          float* __restrict__ of, int MN, int N, int KS)
{
    int i = blockIdx.x * 256 + threadIdx.x;
    if (i >= MN) return;
    float s = 0.f;
    for (int z = 0; z < KS; ++z) s += P[(size_t)z * MN + i];
    s = tanhf(s + bias[i % N]);
    if (EFMT == 1) {
        short h, l; splitf(s, h, l);
        oh[i] = (ushort)h; ol[i] = (ushort)l;
    } else {
        of[i] = s;
    }
}

// FC3: (128x2048) x (2048x62) f32 vector, K-split partials.
__global__ __launch_bounds__(64) void k_fc3_part(
    const float* __restrict__ A, const float* __restrict__ B,
    float* __restrict__ P, int K, int N, int KS)
{
    const int m = blockIdx.x, kz = blockIdx.y;
    const int n = threadIdx.x;
    const int kchunk = K / KS;
    if (n < N) {
        float acc = 0.f;
        const float* Am = A + (size_t)m * K;
        const int ke = (kz + 1) * kchunk;
        for (int k = kz * kchunk; k < ke; ++k)
            acc = fmaf(Am[k], B[(size_t)k * N + n], acc);
        P[((size_t)kz * 128 + m) * N + n] = acc;
    }
}

__global__ void k_fc_epi(const float* __restrict__ P, const float* __restrict__ bias,
                         float* __restrict__ out, int MN, int N, int KS)
{
    int i = blockIdx.x * 256 + threadIdx.x;
    if (i >= MN) return;
    float s = 0.f;
    for (int z = 0; z < KS; ++z) s += P[(size_t)z * MN + i];
    out[i] = s + bias[i % N];
}

// Per-batch DMP segment prep. 1x128, thread = batch.
__global__ void k_traj_start(const float* __restrict__ p, const float* __restrict__ td,
                             float* __restrict__ starts, float* __restrict__ sa,
                             int* __restrict__ sidx)
{
    int b = threadIdx.x;
    const float* pb = p + b * 62;
    float cx = pb[0], cy = pb[1];
    for (int s = 0; s < 20; ++s) {
        float f  = pb[2 + 3 * s];
        float a0 = pb[3 + 3 * s];
        float a1 = pb[4 + 3 * s];
        int idx = (int)fminf(fmaxf(rintf(f), 0.f), 999.f);
        int bs = b * 20 + s;
        sidx[bs] = idx;
        sa[bs * 2 + 0] = a0;
        sa[bs * 2 + 1] = a1;
        starts[bs * 2 + 0] = cx;
        starts[bs * 2 + 1] = cy;
        cx += td[((size_t)idx * 200 + 199) * 2 + 0] * a0;
        cy += td[((size_t)idx * 200 + 199) * 2 + 1] * a1;
    }
}

__global__ void k_traj_main(const float* __restrict__ td, const float* __restrict__ starts,
                            const float* __restrict__ sa, const int* __restrict__ sidx,
                            float* __restrict__ out)
{
    int bs = blockIdx.x;
    int idx = sidx[bs];
    float a0 = sa[bs * 2 + 0], a1 = sa[bs * 2 + 1];
    float s0 = starts[bs * 2 + 0], s1 = starts[bs * 2 + 1];
    const float* row = td + (size_t)idx * 400;
    float* o = out + (size_t)bs * 400;
    for (int e = threadIdx.x; e < 400; e += blockDim.x) {
        float v = row[e];
        o[e] = (e & 1) ? fmaf(v, a1, s1) : fmaf(v, a0, s0);
    }
}

// ---------------------------------------------------------------------------
template<int BPRE>
static void run_all(void* const* d_in, float* out, char* ws, hipStream_t stream)
{
    const float* x   = (const float*)d_in[0];
    const float* w1  = (const float*)d_in[1];
    const float* b1  = (const float*)d_in[2];
    const float* w2  = (const float*)d_in[3];
    const float* b2  = (const float*)d_in[4];
    const float* w3  = (const float*)d_in[5];
    const float* b3  = (const float*)d_in[6];
    const float* w4  = (const float*)d_in[7];
    const float* b4  = (const float*)d_in[8];
    const float* fw1 = (const float*)d_in[9];
    const float* fb1 = (const float*)d_in[10];
    const float* fw2 = (const float*)d_in[11];
    const float* fb2 = (const float*)d_in[12];
    const float* fw3 = (const float*)d_in[13];
    const float* fb3 = (const float*)d_in[14];
    const float* td  = (const float*)d_in[15];

    // ---- workspace layout (bytes), all activation tensors NHWC ----
    uint*   h1   = (uint*)ws;                          // [0, 78,675,968)
    uint*   h2   = (uint*)(ws + 78675968ull);          // 34,668,544
    uint*   h3   = (uint*)ws;                          // [0, 13,107,200)
    ushort* fw1h = (ushort*)(ws + 13107200ull);        // 33,554,432
    ushort* fw1l = (ushort*)(ws + 46661632ull);        // 33,554,432
    ushort* h4h  = (ushort*)(ws + 80216064ull);        // 2,097,152 (NCHW planes)
    ushort* h4l  = (ushort*)(ws + 82313216ull);        // 2,097,152
    ushort* fw2h = (ushort*)(ws + 84410368ull);        // 8,388,608
    ushort* fw2l = (ushort*)(ws + 92798976ull);        // 8,388,608
    float*  part = (float*)(ws + 101187584ull);        // 8,388,608
    ushort* a1h  = (ushort*)(ws + 109576192ull);       // 524,288
    ushort* a1l  = (ushort*)(ws + 110100480ull);       // 524,288
    float*  a2   = (float*)(ws + 110624768ull);        // 1,048,576
    float*  p    = (float*)(ws + 111673344ull);
    float*  starts = (float*)(ws + 111705088ull);
    float*  sa   = (float*)(ws + 111725568ull);
    int*    sidx = (int*)(ws + 111746048ull);
    ushort* w2h = (ushort*)(ws + 113344512ull);
    ushort* w2l = (ushort*)(ws + 113491968ull);
    ushort* w3h = (ushort*)(ws + 113639424ull);
    ushort* w3l = (ushort*)(ws + 114229248ull);
    ushort* w4h = (ushort*)(ws + 114819072ull);
    ushort* w4l = (ushort*)(ws + 117178368ull);        // end 119,537,664

    if (BPRE) {   // permuted split: [n][ci*9+r] -> [n][r*CIN+ci]
        k_wsplit_perm<<<(73728 + 255) / 256, 256, 0, stream>>>(w2, w2h, w2l, 64, 73728);
        k_wsplit_perm<<<(294912 + 255) / 256, 256, 0, stream>>>(w3, w3h, w3l, 128, 294912);
        k_wsplit_perm<<<(1179648 + 255) / 256, 256, 0, stream>>>(w4, w4h, w4l, 256, 1179648);
    }

    // conv1: 3->64, 100 -> pool 49 (direct, NHWC out)
    k_conv_pool_relu<3, 100, 49, 16, 256, 3, 64>
        <<<dim3(10, 4, 128), 256, 0, stream>>>(x, w1, b1, h1);

    // conv2: 64->128, K=576, pooled 23x23 (34 M-tiles/img), N=128
    k_gemm4<0, BPRE, 0, 6, 576, 576, 128, 49, 23, 23, 128, 34>
        <<<dim3(34 * 128, 1), 256, 0, stream>>>(
            h1, nullptr, BPRE ? (const void*)w2h : (const void*)w2,
            BPRE ? (const void*)w2l : nullptr, b2, h2, nullptr);
    // conv3: 128->256, K=1152, pooled 10x10 (7 tiles/img), N=256
    k_gemm4<0, BPRE, 0, 7, 1152, 1152, 256, 23, 10, 10, 256, 7>
        <<<dim3(7 * 128, 2), 256, 0, stream>>>(
            h2, nullptr, BPRE ? (const void*)w3h : (const void*)w3,
            BPRE ? (const void*)w3l : nullptr, b3, h3, nullptr);

    if (BPRE) {   // h1/h2-head dead; build FC weight planes
        k_wsplitT<<<dim3(2048 / 32, 8192 / 32), 256, 0, stream>>>(fw1, fw1h, fw1l, 8192, 2048);
        k_wsplitT<<<dim3(2048 / 32, 2048 / 32), 256, 0, stream>>>(fw2, fw2h, fw2l, 2048, 2048);
    }

    // conv4: 256->512, K=2304, pooled 4x4 (1 tile/img), N=512 -> h4 NCHW planes
    k_gemm4<0, BPRE, 1, 8, 2304, 2304, 512, 10, 4, 4, 512, 1>
        <<<dim3(128, 4), 256, 0, stream>>>(
            h3, nullptr, BPRE ? (const void*)w4h : (const void*)w4,
            BPRE ? (const void*)w4l : nullptr, b4, h4h, h4l);

    // FC1: (128x8192)x(8192x2048), KS=8 partials + tanh -> a1 planes
    k_gemm4<1, BPRE, 2, 0, 8192, 1024, 2048, 1, 1, 1, 1, 1>
        <<<dim3(2, 16, 8), 256, 0, stream>>>(
            h4h, h4l, BPRE ? (const void*)fw1h : (const void*)fw1,
            BPRE ? (const void*)fw1l : nullptr, nullptr, part, nullptr);
    k_fc_epi2<1><<<(128 * 2048 + 255) / 256, 256, 0, stream>>>(
        part, fb1, a1h, a1l, nullptr, 128 * 2048, 2048, 8);
    // FC2: (128x2048)x(2048x2048), KS=8 partials + tanh -> a2 f32
    k_gemm4<1, BPRE, 2, 0, 2048, 256, 2048, 1, 1, 1, 1, 1>
        <<<dim3(2, 16, 8), 256, 0, stream>>>(
            a1h, a1l, BPRE ? (const void*)fw2h : (const void*)fw2,
            BPRE ? (const void*)fw2l : nullptr, nullptr, part, nullptr);
    k_fc_epi2<2><<<(128 * 2048 + 255) / 256, 256, 0, stream>>>(
        part, fb2, nullptr, nullptr, a2, 128 * 2048, 2048, 8);

    // FC3 (f32 vector) + trajectory composition
    k_fc3_part<<<dim3(128, 4), 64, 0, stream>>>(a2, fw3, part, 2048, 62, 4);
    k_fc_epi<<<(128 * 62 + 255) / 256, 256, 0, stream>>>(
        part, fb3, p, 128 * 62, 62, 4);
    k_traj_start<<<1, 128, 0, stream>>>(p, td, starts, sa, sidx);
    k_traj_main<<<2560, 256, 0, stream>>>(td, starts, sa, sidx, out);
}

extern "C" void kernel_launch(void* const* d_in, const int* in_sizes, int n_in,
                              void* d_out, int out_size, void* d_ws, size_t ws_size,
                              hipStream_t stream)
{
    (void)in_sizes; (void)n_in; (void)out_size;
    if (ws_size >= 119537664ull)
        run_all<1>(d_in, (float*)d_out, (char*)d_ws, stream);
    else
        run_all<0>(d_in, (float*)d_out, (char*)d_ws, stream);
}